// Round 7
// baseline (768.344 us; speedup 1.0000x reference)
//
#include <hip/hip_runtime.h>

#define D 128
#define PCHUNK 4096
#define SCAP 8192

typedef short bf16x8 __attribute__((ext_vector_type(8)));
typedef float f32x4 __attribute__((ext_vector_type(4)));

__device__ __forceinline__ ushort f2b(float f){
  unsigned u = __builtin_bit_cast(unsigned, f);
  u += 0x7fffu + ((u >> 16) & 1u);          // round-to-nearest-even
  return (ushort)(u >> 16);
}
__device__ __forceinline__ float b2f(ushort h){
  unsigned u = ((unsigned)h) << 16;
  return __builtin_bit_cast(float, u);
}

// ---------------- P0: coarse bucket histogram (bucket = dst>>8) ----------------
__global__ __launch_bounds__(256) void k_p0(const int* __restrict__ dst,
                                            int* __restrict__ bcnt, int E){
  __shared__ int h[512];
  for (int u=threadIdx.x; u<512; u+=256) h[u]=0;
  __syncthreads();
  for (long long i=(long long)blockIdx.x*256+threadIdx.x; i<E; i+=(long long)gridDim.x*256)
    atomicAdd(&h[dst[i]>>8], 1);
  __syncthreads();
  for (int u=threadIdx.x; u<512; u+=256) if (h[u]) atomicAdd(&bcnt[u], h[u]);
}

// ---------------- P1: scan buckets -> base & cursor ----------------
__global__ void k_bscan(const int* __restrict__ bcnt, int* __restrict__ bbase,
                        int* __restrict__ bcur, int nb, int E){
  __shared__ int sh[1024];
  int t = threadIdx.x;
  int v = (t<nb) ? bcnt[t] : 0;
  sh[t]=v; __syncthreads();
  for (int off=1; off<1024; off<<=1){
    int add = (t>=off)?sh[t-off]:0;
    __syncthreads();
    sh[t]+=add;
    __syncthreads();
  }
  if (t<nb){ int e=sh[t]-v; bbase[t]=e; bcur[t]=e; }
  if (t==nb) bbase[t]=E;
}

// ---------------- P2: LDS-binned partition; pairs packed as src | (dst&255)<<24 ------
__global__ __launch_bounds__(256) void k_part(const int* __restrict__ src,
        const int* __restrict__ dst, int* __restrict__ bcur,
        unsigned* __restrict__ pairs, int E){
  __shared__ int hist[512], offA[512], offB[512], gbase[512];
  __shared__ int sS[PCHUNK], sD[PCHUNK];
  const int t = threadIdx.x;
  const int base = blockIdx.x * PCHUNK;
  const int cnt = min(PCHUNK, E - base);
  for (int u=t; u<512; u+=256) hist[u]=0;
  __syncthreads();
  int rs[16], rd[16];
  #pragma unroll
  for (int j=0;j<16;j++){
    int li = j*256 + t;
    if (li < cnt){
      rs[j]=src[base+li]; rd[j]=dst[base+li];
      atomicAdd(&hist[rd[j]>>8],1);
    } else { rs[j]=0; rd[j]=-1; }
  }
  __syncthreads();
  int *cur=offA, *nxt=offB;
  for (int u=t; u<512; u+=256) cur[u]=hist[u];
  __syncthreads();
  for (int off=1; off<512; off<<=1){
    for (int u=t; u<512; u+=256) nxt[u] = cur[u] + ((u>=off)?cur[u-off]:0);
    __syncthreads();
    int* tmp=cur; cur=nxt; nxt=tmp;
  }
  for (int u=t; u<512; u+=256) nxt[u] = cur[u]-hist[u];
  __syncthreads();
  #pragma unroll
  for (int j=0;j<16;j++){
    if (j*256+t < cnt){
      int b = rd[j]>>8;
      int p = atomicAdd(&nxt[b],1);
      sS[p]=rs[j]; sD[p]=rd[j];
    }
  }
  __syncthreads();
  for (int u=t; u<512; u+=256){
    int c = hist[u];
    if (c>0) gbase[u] = atomicAdd(&bcur[u], c);
  }
  __syncthreads();
  #pragma unroll
  for (int j=0;j<16;j++){
    int idx = j*256+t;
    if (idx<cnt){
      int d = sD[idx]; int b = d>>8;
      int gpos = gbase[b] + (idx - (cur[b]-hist[b]));
      pairs[gpos] = (unsigned)sS[idx] | ((unsigned)(d & 255) << 24);
    }
  }
}

// ---------------- P3: per-bucket exact counting sort -> slots + offs ----------------
__global__ __launch_bounds__(256) void k_sortb(const unsigned* __restrict__ pairs,
        const int* __restrict__ bbase, int* __restrict__ offs,
        int* __restrict__ slots, int N, int NB){
  __shared__ int nh[256], nc[256], sc[256];
  __shared__ int stage[SCAP];
  const int b = blockIdx.x, t = threadIdx.x;
  const int base = bbase[b];
  const int cnt  = bbase[b+1] - base;
  nh[t]=0; __syncthreads();
  for (int i=t;i<cnt;i+=256) atomicAdd(&nh[pairs[base+i] >> 24],1);
  __syncthreads();
  int v = nh[t];
  sc[t]=v; __syncthreads();
  for (int off=1; off<256; off<<=1){
    int add = (t>=off)?sc[t-off]:0;
    __syncthreads();
    sc[t]+=add;
    __syncthreads();
  }
  int excl = sc[t]-v;
  nc[t]=excl;
  int node = (b<<8)+t;
  if (node<N) offs[node]=base+excl;
  if (b==NB-1 && t==0) offs[N]=bbase[NB];
  __syncthreads();
  if (cnt<=SCAP){
    for (int i=t;i<cnt;i+=256){
      unsigned p = pairs[base+i];
      int pos = atomicAdd(&nc[p >> 24],1);
      stage[pos]=(int)(p & 0xffffffu);
    }
    __syncthreads();
    for (int i=t;i<cnt;i+=256) slots[base+i]=stage[i];
  } else {
    for (int i=t;i<cnt;i+=256){
      unsigned p = pairs[base+i];
      int pos = atomicAdd(&nc[p >> 24],1);
      slots[base+pos]=(int)(p & 0xffffffu);
    }
  }
}

// ---------------- f32 -> bf16 cast ----------------
__global__ __launch_bounds__(256) void k_xcast(const float* __restrict__ x,
                                               ushort* __restrict__ xb, long long n4){
  long long i = (long long)blockIdx.x*256 + threadIdx.x;
  const long long stride = (long long)gridDim.x*256;
  for (; i < n4; i += stride){
    float4 v = reinterpret_cast<const float4*>(x)[i];
    ushort4 o;
    o.x = f2b(v.x); o.y = f2b(v.y); o.z = f2b(v.z); o.w = f2b(v.w);
    reinterpret_cast<ushort4*>(xb)[i] = o;
  }
}

// ---------------- weight transpose+cast: Wb[c*K + k0 + k] = bf16(W[k][c]) ----------------
__global__ void k_wt(const float* __restrict__ W, ushort* __restrict__ Wb, int K, int k0){
  int idx = blockIdx.x*256 + threadIdx.x;   // 0..16383
  int k = idx >> 7, c = idx & 127;
  Wb[(size_t)c*K + k0 + k] = f2b(W[idx]);
}

// ---------------- XCD-sliced gather-mean ----------------
// Block b handles channel slice (b&7) of node chunk (b>>3). Under round-robin
// block->XCD dispatch, each XCD touches only a 3.2 MB table slice -> L2-resident;
// slots stream is read nontemporal so it doesn't evict the slice. One wave per
// node: lane = (edge-slot e = lane>>3, channel pair = lane&7); 16 edges/round;
// final reduce over e via 3 shuffles. Correct under ANY block->XCD mapping.
__global__ __launch_bounds__(256) void k_gatherb(const ushort* __restrict__ Xb,
        const int* __restrict__ slots, const int* __restrict__ offs,
        ushort* __restrict__ meanb, int N){
  const int slice = blockIdx.x & 7;
  const int node  = (blockIdx.x >> 3)*4 + (threadIdx.x >> 6);
  if (node >= N) return;
  const int lane = threadIdx.x & 63;
  const int e = lane >> 3;                       // edge sub-slot 0..7
  const unsigned c2 = slice*16 + (lane & 7)*2;   // ushort offset within row
  const int beg = offs[node], end = offs[node+1];
  const int deg = end - beg;
  float sx = 0.f, sy = 0.f;
  int j = beg;
  int r = deg >> 4;                              // full 16-edge rounds
  if (r > 0){
    int i0 = __builtin_nontemporal_load(&slots[j + e]);
    int i1 = __builtin_nontemporal_load(&slots[j + 8 + e]);
    for (; r > 1; --r){
      j += 16;
      int n0 = __builtin_nontemporal_load(&slots[j + e]);      // prefetch next round
      int n1 = __builtin_nontemporal_load(&slots[j + 8 + e]);
      unsigned u0 = *reinterpret_cast<const unsigned*>(&Xb[(size_t)i0*D + c2]);
      unsigned u1 = *reinterpret_cast<const unsigned*>(&Xb[(size_t)i1*D + c2]);
      sx += b2f((ushort)u0); sy += b2f((ushort)(u0>>16));
      sx += b2f((ushort)u1); sy += b2f((ushort)(u1>>16));
      i0 = n0; i1 = n1;
    }
    unsigned u0 = *reinterpret_cast<const unsigned*>(&Xb[(size_t)i0*D + c2]);
    unsigned u1 = *reinterpret_cast<const unsigned*>(&Xb[(size_t)i1*D + c2]);
    sx += b2f((ushort)u0); sy += b2f((ushort)(u0>>16));
    sx += b2f((ushort)u1); sy += b2f((ushort)(u1>>16));
    j += 16;
  }
  // tail: up to 15 edges, lane covers j+e and j+8+e guarded
  if (j + e < end){
    int i0 = __builtin_nontemporal_load(&slots[j + e]);
    unsigned u0 = *reinterpret_cast<const unsigned*>(&Xb[(size_t)i0*D + c2]);
    sx += b2f((ushort)u0); sy += b2f((ushort)(u0>>16));
  }
  if (j + 8 + e < end){
    int i1 = __builtin_nontemporal_load(&slots[j + 8 + e]);
    unsigned u1 = *reinterpret_cast<const unsigned*>(&Xb[(size_t)i1*D + c2]);
    sx += b2f((ushort)u1); sy += b2f((ushort)(u1>>16));
  }
  // reduce over e (stride-8 lanes share a channel pair)
  sx += __shfl_xor(sx, 8);  sy += __shfl_xor(sy, 8);
  sx += __shfl_xor(sx, 16); sy += __shfl_xor(sy, 16);
  sx += __shfl_xor(sx, 32); sy += __shfl_xor(sy, 32);
  if (e == 0){
    float rc = deg > 0 ? 1.0f/(float)deg : 0.f;
    unsigned o = (unsigned)f2b(sx*rc) | ((unsigned)f2b(sy*rc) << 16);
    __builtin_nontemporal_store(o,
        reinterpret_cast<unsigned*>(meanb + (size_t)node*D + c2));
  }
}

// ---------------- persistent 2-phase pipelined MFMA GEMM, 4-deep lookahead ----------------
// 64x128 tile, 4 waves (2x2). C = [A0 | A1] @ Wb^T + bias (K=256),
// optional fused skip Ck = A0 @ Wk^T + biasK (K=128).
// Grid = 512 persistent blocks (2/CU); pipeline never drains across tiles.
template<bool SKIP>
__global__ __launch_bounds__(256, 2) void k_mfma(
    const ushort* __restrict__ A0, const ushort* __restrict__ A1,
    const ushort* __restrict__ Wb, const ushort* __restrict__ Wk,
    const float* __restrict__ bias, const float* __restrict__ biasK,
    ushort* __restrict__ C, ushort* __restrict__ Ck,
    float* __restrict__ gS, float* __restrict__ gQ,
    float* __restrict__ gSK, float* __restrict__ gQK, int N, int NT)
{
  __shared__ ushort At[2][64][40];
  __shared__ ushort Wt[2][128][40];
  __shared__ ushort Wkt[SKIP ? 2*128*40 : 1];
  __shared__ float shS[128], shQ[128], shSK[SKIP?128:1], shQK[SKIP?128:1];
  const int tid = threadIdx.x;
  if (tid < 128){ shS[tid]=0.f; shQ[tid]=0.f; if (SKIP){ shSK[tid]=0.f; shQK[tid]=0.f; } }
  const int bid = blockIdx.x, gridN = gridDim.x;
  const int lane = tid & 63, wid = tid >> 6;
  const int wr = wid >> 1, wc = wid & 1;
  const int lr = lane & 15, kq = lane >> 4;
  const int srA = tid >> 2, s8A = (tid & 3) * 8;
  const int srW = tid >> 2, s8W = (tid & 3) * 8;

  // 4 named register load-sets (period 4 divides the 8-step tile -> static naming)
  int4 va0, va1, va2, va3;
  int4 w0a,w0b, w1a,w1b, w2a,w2b, w3a,w3b;
  int4 k0a,k0b, k1a,k1b, k2a,k2b, k3a,k3b;

#define LOADSET(S, GT, TT) { \
    int grow_ = (GT)*64 + srA; if (grow_ >= N) grow_ = N-1; \
    const ushort* As_ = ((TT) >= 4) ? A1 : A0; \
    va##S = *reinterpret_cast<const int4*>(&As_[(size_t)grow_*D + ((TT)&3)*32 + s8A]); \
    w##S##a = *reinterpret_cast<const int4*>(&Wb[(size_t)srW*256 + (TT)*32 + s8W]); \
    w##S##b = *reinterpret_cast<const int4*>(&Wb[(size_t)(srW+64)*256 + (TT)*32 + s8W]); \
    if (SKIP && (TT) < 4){ \
      k##S##a = *reinterpret_cast<const int4*>(&Wk[(size_t)srW*128 + (TT)*32 + s8W]); \
      k##S##b = *reinterpret_cast<const int4*>(&Wk[(size_t)(srW+64)*128 + (TT)*32 + s8W]); \
    } }

#define WRITESET(S, BW, TT) { \
    *reinterpret_cast<int4*>(&At[BW][srA][s8A]) = va##S; \
    *reinterpret_cast<int4*>(&Wt[BW][srW][s8W]) = w##S##a; \
    *reinterpret_cast<int4*>(&Wt[BW][srW+64][s8W]) = w##S##b; \
    if (SKIP && (TT) < 4){ \
      *reinterpret_cast<int4*>(&Wkt[((BW)*128 + srW)*40 + s8W]) = k##S##a; \
      *reinterpret_cast<int4*>(&Wkt[((BW)*128 + srW + 64)*40 + s8W]) = k##S##b; \
    } }

#define PBAR() { asm volatile("s_waitcnt lgkmcnt(0)" ::: "memory"); \
    __builtin_amdgcn_s_barrier(); __builtin_amdgcn_sched_barrier(0); }

#define STEPBODY(BR, WITHK, ...) { \
    bf16x8 af0 = *reinterpret_cast<const bf16x8*>(&At[BR][32*wr + lr][kq*8]); \
    bf16x8 af1 = *reinterpret_cast<const bf16x8*>(&At[BR][32*wr + 16 + lr][kq*8]); \
    bf16x8 bw0 = *reinterpret_cast<const bf16x8*>(&Wt[BR][64*wc + lr][kq*8]); \
    bf16x8 bw1 = *reinterpret_cast<const bf16x8*>(&Wt[BR][64*wc + 16 + lr][kq*8]); \
    bf16x8 bw2 = *reinterpret_cast<const bf16x8*>(&Wt[BR][64*wc + 32 + lr][kq*8]); \
    bf16x8 bw3 = *reinterpret_cast<const bf16x8*>(&Wt[BR][64*wc + 48 + lr][kq*8]); \
    bf16x8 bk0{}, bk1{}, bk2{}, bk3{}; \
    if (SKIP && (WITHK)){ \
      bk0 = *reinterpret_cast<const bf16x8*>(&Wkt[((BR)*128 + 64*wc + lr)*40 + kq*8]); \
      bk1 = *reinterpret_cast<const bf16x8*>(&Wkt[((BR)*128 + 64*wc + 16 + lr)*40 + kq*8]); \
      bk2 = *reinterpret_cast<const bf16x8*>(&Wkt[((BR)*128 + 64*wc + 32 + lr)*40 + kq*8]); \
      bk3 = *reinterpret_cast<const bf16x8*>(&Wkt[((BR)*128 + 64*wc + 48 + lr)*40 + kq*8]); \
    } \
    __VA_ARGS__; \
    acc[0][0] = __builtin_amdgcn_mfma_f32_16x16x32_bf16(af0, bw0, acc[0][0], 0,0,0); \
    acc[0][1] = __builtin_amdgcn_mfma_f32_16x16x32_bf16(af0, bw1, acc[0][1], 0,0,0); \
    acc[0][2] = __builtin_amdgcn_mfma_f32_16x16x32_bf16(af0, bw2, acc[0][2], 0,0,0); \
    acc[0][3] = __builtin_amdgcn_mfma_f32_16x16x32_bf16(af0, bw3, acc[0][3], 0,0,0); \
    acc[1][0] = __builtin_amdgcn_mfma_f32_16x16x32_bf16(af1, bw0, acc[1][0], 0,0,0); \
    acc[1][1] = __builtin_amdgcn_mfma_f32_16x16x32_bf16(af1, bw1, acc[1][1], 0,0,0); \
    acc[1][2] = __builtin_amdgcn_mfma_f32_16x16x32_bf16(af1, bw2, acc[1][2], 0,0,0); \
    acc[1][3] = __builtin_amdgcn_mfma_f32_16x16x32_bf16(af1, bw3, acc[1][3], 0,0,0); \
    if (SKIP && (WITHK)){ \
      accK[0][0] = __builtin_amdgcn_mfma_f32_16x16x32_bf16(af0, bk0, accK[0][0], 0,0,0); \
      accK[0][1] = __builtin_amdgcn_mfma_f32_16x16x32_bf16(af0, bk1, accK[0][1], 0,0,0); \
      accK[0][2] = __builtin_amdgcn_mfma_f32_16x16x32_bf16(af0, bk2, accK[0][2], 0,0,0); \
      accK[0][3] = __builtin_amdgcn_mfma_f32_16x16x32_bf16(af0, bk3, accK[0][3], 0,0,0); \
      accK[1][0] = __builtin_amdgcn_mfma_f32_16x16x32_bf16(af1, bk0, accK[1][0], 0,0,0); \
      accK[1][1] = __builtin_amdgcn_mfma_f32_16x16x32_bf16(af1, bk1, accK[1][1], 0,0,0); \
      accK[1][2] = __builtin_amdgcn_mfma_f32_16x16x32_bf16(af1, bk2, accK[1][2], 0,0,0); \
      accK[1][3] = __builtin_amdgcn_mfma_f32_16x16x32_bf16(af1, bk3, accK[1][3], 0,0,0); \
    } }

  f32x4 acc[2][4], accK[SKIP?2:1][SKIP?4:1];
  #pragma unroll
  for (int m=0;m<2;m++)
    #pragma unroll
    for (int n=0;n<4;n++){
      acc[m][n] = (f32x4){0.f,0.f,0.f,0.f};
      if (SKIP) accK[m][n] = (f32x4){0.f,0.f,0.f,0.f};
    }
  float bs[4]={0,0,0,0}, bq[4]={0,0,0,0}, bsk[4]={0,0,0,0}, bqk[4]={0,0,0,0};
  float bv[4], bkv[4];
  #pragma unroll
  for (int n=0;n<4;n++){
    bv[n] = bias[64*wc + 16*n + lr];
    bkv[n] = SKIP ? biasK[64*wc + 16*n + lr] : 0.f;
  }

  // prologue: prime 4 sets (steps 0..3 of first tile), stage step 0 into buf0
  {
    const int t0 = bid;
    LOADSET(0, t0, 0);
    LOADSET(1, t0, 1);
    LOADSET(2, t0, 2);
    LOADSET(3, t0, 3);
    WRITESET(0, 0, 0);
    PBAR();
  }

  for (int tile = bid; tile < NT; tile += gridN){
    const int tnext = tile + gridN;
    const bool hasnext = (tnext < NT);
    STEPBODY(0, 1, LOADSET(0, tile, 4));
    WRITESET(1, 1, 1); PBAR();
    STEPBODY(1, 1, LOADSET(1, tile, 5));
    WRITESET(2, 0, 2); PBAR();
    STEPBODY(0, 1, LOADSET(2, tile, 6));
    WRITESET(3, 1, 3); PBAR();
    STEPBODY(1, 1, LOADSET(3, tile, 7));
    WRITESET(0, 0, 4); PBAR();
    STEPBODY(0, 0, if (hasnext) LOADSET(0, tnext, 0));
    WRITESET(1, 1, 5); PBAR();
    STEPBODY(1, 0, if (hasnext) LOADSET(1, tnext, 1));
    WRITESET(2, 0, 6); PBAR();
    STEPBODY(0, 0, if (hasnext) LOADSET(2, tnext, 2));
    WRITESET(3, 1, 7); PBAR();
    STEPBODY(1, 0, if (hasnext) LOADSET(3, tnext, 3));
    if (hasnext){ WRITESET(0, 0, 0); PBAR(); }

    // per-tile epilogue (stores overlap next tile's in-flight loads / ds_reads)
    #pragma unroll
    for (int m=0;m<2;m++){
      #pragma unroll
      for (int r=0;r<4;r++){
        int row = tile*64 + 32*wr + 16*m + kq*4 + r;
        if (row < N){
          #pragma unroll
          for (int n=0;n<4;n++){
            int col = 64*wc + 16*n + lr;
            float v = acc[m][n][r] + bv[n];
            C[(size_t)row*D + col] = f2b(v);
            bs[n] += v; bq[n] += v*v;
            if (SKIP){
              float u = accK[m][n][r] + bkv[n];
              Ck[(size_t)row*D + col] = f2b(u);
              bsk[n] += u; bqk[n] += u*u;
            }
          }
        }
      }
    }
    #pragma unroll
    for (int m=0;m<2;m++)
      #pragma unroll
      for (int n=0;n<4;n++){
        acc[m][n] = (f32x4){0.f,0.f,0.f,0.f};
        if (SKIP) accK[m][n] = (f32x4){0.f,0.f,0.f,0.f};
      }
  }
#undef LOADSET
#undef WRITESET
#undef PBAR
#undef STEPBODY

  // one stat-reduction per block
  #pragma unroll
  for (int n=0;n<4;n++){
    float s = bs[n], q = bq[n];
    s += __shfl_xor(s,16); s += __shfl_xor(s,32);
    q += __shfl_xor(q,16); q += __shfl_xor(q,32);
    if (kq == 0){
      int col = 64*wc + 16*n + lr;
      atomicAdd(&shS[col], s);
      atomicAdd(&shQ[col], q);
    }
    if (SKIP){
      float sk = bsk[n], qk = bqk[n];
      sk += __shfl_xor(sk,16); sk += __shfl_xor(sk,32);
      qk += __shfl_xor(qk,16); qk += __shfl_xor(qk,32);
      if (kq == 0){
        int col = 64*wc + 16*n + lr;
        atomicAdd(&shSK[col], sk);
        atomicAdd(&shQK[col], qk);
      }
    }
  }
  __syncthreads();
  if (tid < 128){
    unsafeAtomicAdd(&gS[tid], shS[tid]);
    unsafeAtomicAdd(&gQ[tid], shQ[tid]);
    if (SKIP){
      unsafeAtomicAdd(&gSK[tid], shSK[tid]);
      unsafeAtomicAdd(&gQK[tid], shQK[tid]);
    }
  }
}

// ---------------- BN finalize ----------------
__global__ void k_bnfin(const float* __restrict__ sum, const float* __restrict__ sq,
                        const float* __restrict__ g, const float* __restrict__ be,
                        float* __restrict__ bnA, float* __restrict__ bnB, float invN){
  int c = threadIdx.x;
  float m = sum[c]*invN;
  float v = sq[c]*invN - m*m;
  float a = g[c]*rsqrtf(fmaxf(v, 0.f) + 1e-5f);
  bnA[c] = a;
  bnB[c] = be[c] - m*a;
}

// ---------------- BN + ReLU, bf16 in -> bf16 out ----------------
__global__ __launch_bounds__(256) void k_bnrelub(const ushort* __restrict__ hpre,
      ushort* __restrict__ hb,
      const float* __restrict__ A, const float* __restrict__ Bp, long long n4){
  long long i = (long long)blockIdx.x*256 + threadIdx.x;
  const long long stride = (long long)gridDim.x*256;
  for (; i < n4; i += stride){
    int c = ((int)(i & 31)) << 2;
    float4 a = *reinterpret_cast<const float4*>(A + c);
    float4 b = *reinterpret_cast<const float4*>(Bp + c);
    ushort4 hv = reinterpret_cast<const ushort4*>(hpre)[i];
    ushort4 o;
    o.x = f2b(fmaxf(a.x*b2f(hv.x) + b.x, 0.f));
    o.y = f2b(fmaxf(a.y*b2f(hv.y) + b.y, 0.f));
    o.z = f2b(fmaxf(a.z*b2f(hv.z) + b.z, 0.f));
    o.w = f2b(fmaxf(a.w*b2f(hv.w) + b.w, 0.f));
    reinterpret_cast<ushort4*>(hb)[i] = o;
  }
}

// ---------------- final: out = relu(bn2(h2) + bn3(skip)), f32 out ----------------
__global__ __launch_bounds__(256) void k_final(const ushort* __restrict__ h2,
      const ushort* __restrict__ sk, float* __restrict__ out,
      const float* __restrict__ A2, const float* __restrict__ B2,
      const float* __restrict__ A3, const float* __restrict__ B3, long long n4){
  long long i = (long long)blockIdx.x*256 + threadIdx.x;
  const long long stride = (long long)gridDim.x*256;
  for (; i < n4; i += stride){
    int c = ((int)(i & 31)) << 2;
    float4 a2 = *reinterpret_cast<const float4*>(A2 + c);
    float4 b2 = *reinterpret_cast<const float4*>(B2 + c);
    float4 a3 = *reinterpret_cast<const float4*>(A3 + c);
    float4 b3 = *reinterpret_cast<const float4*>(B3 + c);
    ushort4 h = reinterpret_cast<const ushort4*>(h2)[i];
    ushort4 s = reinterpret_cast<const ushort4*>(sk)[i];
    float4 v;
    v.x = fmaxf(a2.x*b2f(h.x) + b2.x + a3.x*b2f(s.x) + b3.x, 0.f);
    v.y = fmaxf(a2.y*b2f(h.y) + b2.y + a3.y*b2f(s.y) + b3.y, 0.f);
    v.z = fmaxf(a2.z*b2f(h.z) + b2.z + a3.z*b2f(s.z) + b3.z, 0.f);
    v.w = fmaxf(a2.w*b2f(h.w) + b2.w + a3.w*b2f(s.w) + b3.w, 0.f);
    reinterpret_cast<float4*>(out)[i] = v;
  }
}

extern "C" void kernel_launch(void* const* d_in, const int* in_sizes, int n_in,
                              void* d_out, int out_size, void* d_ws, size_t ws_size,
                              hipStream_t stream) {
  const float* x        = (const float*)d_in[0];
  const int*   src      = (const int*)  d_in[1];
  const int*   dst      = (const int*)  d_in[2];
  const float* w_self1  = (const float*)d_in[3];
  const float* w_neigh1 = (const float*)d_in[4];
  const float* b1       = (const float*)d_in[5];
  const float* w_self2  = (const float*)d_in[6];
  const float* w_neigh2 = (const float*)d_in[7];
  const float* b2       = (const float*)d_in[8];
  const float* w_skip   = (const float*)d_in[9];
  const float* b_skip   = (const float*)d_in[10];
  const float* g1       = (const float*)d_in[11];
  const float* be1      = (const float*)d_in[12];
  const float* g2       = (const float*)d_in[13];
  const float* be2      = (const float*)d_in[14];
  const float* g3       = (const float*)d_in[15];
  const float* be3      = (const float*)d_in[16];
  (void)n_in; (void)ws_size;

  const int N = in_sizes[0] / D;
  const int E = in_sizes[1];
  const int NB = (N + 255) >> 8;
  float* out = (float*)d_out;

  // ---- workspace layout ----
  char* p = (char*)d_ws;
  const size_t nd2 = (((size_t)N * D * 2) + 255) / 256 * 256;   // bf16 [N][D]
  ushort* meanb  = (ushort*)p; p += nd2;
  ushort* h1b    = (ushort*)p; p += nd2;
  ushort* hpre_b = (ushort*)p; p += nd2;     // h1pre, then h2pre (aliased)
  ushort* skip_b = (ushort*)p; p += nd2;
  ushort* Wb1    = (ushort*)p; p += 256*128*2;
  ushort* Wb2    = (ushort*)p; p += 256*128*2;
  ushort* Wb3    = (ushort*)p; p += 128*128*2;
  int*    offs   = (int*)p;   p += (((size_t)(N+1)*4) + 255) / 256 * 256;
  int*    bcnt   = (int*)p;   p += 2304;
  float*  st     = (float*)p; p += 1536*sizeof(float);
  int*    bbase  = (int*)p;   p += 2304;
  int*    bcur   = (int*)p;   p += 2048;
  float *sum1=st,      *sq1=st+128,  *sum2=st+256, *sq2=st+384, *sum3=st+512, *sq3=st+640;
  float *bnA1=st+768,  *bnB1=st+896, *bnA2=st+1024,*bnB2=st+1152,*bnA3=st+1280,*bnB3=st+1408;

  // scratch in d_out (dead before k_final rewrites all of d_out)
  const size_t slpad = (((size_t)E*4) + 255) / 256 * 256;
  const size_t xbpad = (((size_t)N*D*2) + 255) / 256 * 256;
  int*      slots = (int*)d_out;
  ushort*   xb    = (ushort*)((char*)d_out + slpad);
  unsigned* pairs = (unsigned*)((char*)d_out + slpad + xbpad);

  hipMemsetAsync(bcnt, 0, 2304 + 1536*sizeof(float), stream);

  const long long n4 = (long long)N * D / 4;

  // --- casts / weight prep ---
  k_xcast<<<2048, 256, 0, stream>>>(x, xb, n4);
  k_wt<<<64, 256, 0, stream>>>(w_self1,  Wb1, 256, 0);
  k_wt<<<64, 256, 0, stream>>>(w_neigh1, Wb1, 256, 128);
  k_wt<<<64, 256, 0, stream>>>(w_self2,  Wb2, 256, 0);
  k_wt<<<64, 256, 0, stream>>>(w_neigh2, Wb2, 256, 128);
  k_wt<<<64, 256, 0, stream>>>(w_skip,   Wb3, 128, 0);

  // --- CSR build via 2-level counting sort ---
  k_p0<<<1024, 256, 0, stream>>>(dst, bcnt, E);
  k_bscan<<<1, 1024, 0, stream>>>(bcnt, bbase, bcur, NB, E);
  k_part<<<(E + PCHUNK - 1)/PCHUNK, 256, 0, stream>>>(src, dst, bcur, pairs, E);
  k_sortb<<<NB, 256, 0, stream>>>(pairs, bbase, offs, slots, N, NB);

  const int gablocks = ((N + 3) / 4) * 8;     // x8 channel slices (XCD-aware)
  const int NT = (N + 63) / 64;
  const int gpersist = 512;                   // 2 persistent blocks per CU
  const float invN = 1.0f / (float)N;

  // --- layer 1 ---
  k_gatherb<<<gablocks, 256, 0, stream>>>(xb, slots, offs, meanb, N);
  k_mfma<false><<<gpersist, 256, 0, stream>>>(xb, meanb, Wb1, nullptr, b1, nullptr,
                                              hpre_b, nullptr, sum1, sq1, nullptr, nullptr, N, NT);
  k_bnfin<<<1, 128, 0, stream>>>(sum1, sq1, g1, be1, bnA1, bnB1, invN);
  k_bnrelub<<<4096, 256, 0, stream>>>(hpre_b, h1b, bnA1, bnB1, n4);

  // --- layer 2 aggregation ---
  k_gatherb<<<gablocks, 256, 0, stream>>>(h1b, slots, offs, meanb, N);

  // fused layer-2 + skip GEMM (shares A fragments; h1b read once)
  k_mfma<true><<<gpersist, 256, 0, stream>>>(h1b, meanb, Wb2, Wb3, b2, b_skip,
                                             hpre_b, skip_b, sum2, sq2, sum3, sq3, N, NT);
  k_bnfin<<<1, 128, 0, stream>>>(sum2, sq2, g2, be2, bnA2, bnB2, invN);
  k_bnfin<<<1, 128, 0, stream>>>(sum3, sq3, g3, be3, bnA3, bnB3, invN);

  k_final<<<4096, 256, 0, stream>>>(hpre_b, skip_b, out, bnA2, bnB2, bnA3, bnB3, n4);
}

// Round 8
// 329.770 us; speedup vs baseline: 2.3299x; 2.3299x over previous
//
#include <hip/hip_runtime.h>

#define D 128
#define PCHUNK 4096
#define SCAP 8192

typedef short bf16x8 __attribute__((ext_vector_type(8)));
typedef float f32x4 __attribute__((ext_vector_type(4)));

__device__ __forceinline__ ushort f2b(float f){
  unsigned u = __builtin_bit_cast(unsigned, f);
  u += 0x7fffu + ((u >> 16) & 1u);          // round-to-nearest-even
  return (ushort)(u >> 16);
}
__device__ __forceinline__ float b2f(ushort h){
  unsigned u = ((unsigned)h) << 16;
  return __builtin_bit_cast(float, u);
}

// ---------------- P0: coarse bucket histogram (bucket = dst>>8) ----------------
__global__ __launch_bounds__(256) void k_p0(const int* __restrict__ dst,
                                            int* __restrict__ bcnt, int E){
  __shared__ int h[512];
  for (int u=threadIdx.x; u<512; u+=256) h[u]=0;
  __syncthreads();
  for (long long i=(long long)blockIdx.x*256+threadIdx.x; i<E; i+=(long long)gridDim.x*256)
    atomicAdd(&h[dst[i]>>8], 1);
  __syncthreads();
  for (int u=threadIdx.x; u<512; u+=256) if (h[u]) atomicAdd(&bcnt[u], h[u]);
}

// ---------------- P1: scan buckets -> base & cursor ----------------
__global__ void k_bscan(const int* __restrict__ bcnt, int* __restrict__ bbase,
                        int* __restrict__ bcur, int nb, int E){
  __shared__ int sh[1024];
  int t = threadIdx.x;
  int v = (t<nb) ? bcnt[t] : 0;
  sh[t]=v; __syncthreads();
  for (int off=1; off<1024; off<<=1){
    int add = (t>=off)?sh[t-off]:0;
    __syncthreads();
    sh[t]+=add;
    __syncthreads();
  }
  if (t<nb){ int e=sh[t]-v; bbase[t]=e; bcur[t]=e; }
  if (t==nb) bbase[t]=E;
}

// ---------------- P2: LDS-binned partition; pairs packed as src | (dst&255)<<24 ------
__global__ __launch_bounds__(256) void k_part(const int* __restrict__ src,
        const int* __restrict__ dst, int* __restrict__ bcur,
        unsigned* __restrict__ pairs, int E){
  __shared__ int hist[512], offA[512], offB[512], gbase[512];
  __shared__ int sS[PCHUNK], sD[PCHUNK];
  const int t = threadIdx.x;
  const int base = blockIdx.x * PCHUNK;
  const int cnt = min(PCHUNK, E - base);
  for (int u=t; u<512; u+=256) hist[u]=0;
  __syncthreads();
  int rs[16], rd[16];
  #pragma unroll
  for (int j=0;j<16;j++){
    int li = j*256 + t;
    if (li < cnt){
      rs[j]=src[base+li]; rd[j]=dst[base+li];
      atomicAdd(&hist[rd[j]>>8],1);
    } else { rs[j]=0; rd[j]=-1; }
  }
  __syncthreads();
  int *cur=offA, *nxt=offB;
  for (int u=t; u<512; u+=256) cur[u]=hist[u];
  __syncthreads();
  for (int off=1; off<512; off<<=1){
    for (int u=t; u<512; u+=256) nxt[u] = cur[u] + ((u>=off)?cur[u-off]:0);
    __syncthreads();
    int* tmp=cur; cur=nxt; nxt=tmp;
  }
  for (int u=t; u<512; u+=256) nxt[u] = cur[u]-hist[u];
  __syncthreads();
  #pragma unroll
  for (int j=0;j<16;j++){
    if (j*256+t < cnt){
      int b = rd[j]>>8;
      int p = atomicAdd(&nxt[b],1);
      sS[p]=rs[j]; sD[p]=rd[j];
    }
  }
  __syncthreads();
  for (int u=t; u<512; u+=256){
    int c = hist[u];
    if (c>0) gbase[u] = atomicAdd(&bcur[u], c);
  }
  __syncthreads();
  #pragma unroll
  for (int j=0;j<16;j++){
    int idx = j*256+t;
    if (idx<cnt){
      int d = sD[idx]; int b = d>>8;
      int gpos = gbase[b] + (idx - (cur[b]-hist[b]));
      pairs[gpos] = (unsigned)sS[idx] | ((unsigned)(d & 255) << 24);
    }
  }
}

// ---------------- P3: per-bucket exact counting sort -> slots + offs ----------------
__global__ __launch_bounds__(256) void k_sortb(const unsigned* __restrict__ pairs,
        const int* __restrict__ bbase, int* __restrict__ offs,
        int* __restrict__ slots, int N, int NB){
  __shared__ int nh[256], nc[256], sc[256];
  __shared__ int stage[SCAP];
  const int b = blockIdx.x, t = threadIdx.x;
  const int base = bbase[b];
  const int cnt  = bbase[b+1] - base;
  nh[t]=0; __syncthreads();
  for (int i=t;i<cnt;i+=256) atomicAdd(&nh[pairs[base+i] >> 24],1);
  __syncthreads();
  int v = nh[t];
  sc[t]=v; __syncthreads();
  for (int off=1; off<256; off<<=1){
    int add = (t>=off)?sc[t-off]:0;
    __syncthreads();
    sc[t]+=add;
    __syncthreads();
  }
  int excl = sc[t]-v;
  nc[t]=excl;
  int node = (b<<8)+t;
  if (node<N) offs[node]=base+excl;
  if (b==NB-1 && t==0) offs[N]=bbase[NB];
  __syncthreads();
  if (cnt<=SCAP){
    for (int i=t;i<cnt;i+=256){
      unsigned p = pairs[base+i];
      int pos = atomicAdd(&nc[p >> 24],1);
      stage[pos]=(int)(p & 0xffffffu);
    }
    __syncthreads();
    for (int i=t;i<cnt;i+=256) slots[base+i]=stage[i];
  } else {
    for (int i=t;i<cnt;i+=256){
      unsigned p = pairs[base+i];
      int pos = atomicAdd(&nc[p >> 24],1);
      slots[base+pos]=(int)(p & 0xffffffu);
    }
  }
}

// ---------------- f32 -> bf16 cast ----------------
__global__ __launch_bounds__(256) void k_xcast(const float* __restrict__ x,
                                               ushort* __restrict__ xb, long long n4){
  long long i = (long long)blockIdx.x*256 + threadIdx.x;
  const long long stride = (long long)gridDim.x*256;
  for (; i < n4; i += stride){
    float4 v = reinterpret_cast<const float4*>(x)[i];
    ushort4 o;
    o.x = f2b(v.x); o.y = f2b(v.y); o.z = f2b(v.z); o.w = f2b(v.w);
    reinterpret_cast<ushort4*>(xb)[i] = o;
  }
}

// ---------------- weight transpose+cast: Wb[c*K + k0 + k] = bf16(W[k][c]) ----------------
__global__ void k_wt(const float* __restrict__ W, ushort* __restrict__ Wb, int K, int k0){
  int idx = blockIdx.x*256 + threadIdx.x;   // 0..16383
  int k = idx >> 7, c = idx & 127;
  Wb[(size_t)c*K + k0 + k] = f2b(W[idx]);
}

// ---------------- gather-mean (bf16 in/out): 64 threads/node, pipelined 8-edge groups ----
// (R5 version — best measured: 67.7 us, 177 MB fetch; random-fill-bound floor)
__global__ __launch_bounds__(256) void k_gatherb(const ushort* __restrict__ Xb,
        const int* __restrict__ slots, const int* __restrict__ offs,
        ushort* __restrict__ meanb, int N){
  int node = blockIdx.x*4 + (threadIdx.x >> 6);
  int c2 = (threadIdx.x & 63) * 2;            // this lane's channel pair
  if (node >= N) return;
  const int beg = offs[node], end = offs[node+1];
  float sx0=0,sy0=0,sx1=0,sy1=0,sx2=0,sy2=0,sx3=0,sy3=0;
  int j = beg;
  while (j < end && (j & 3)){
    unsigned u = *reinterpret_cast<const unsigned*>(&Xb[(size_t)slots[j]*D + c2]);
    sx0 += b2f((ushort)u); sy0 += b2f((ushort)(u>>16));
    ++j;
  }
  const int nfull = (end - j) >> 2;
  const int4* sp = reinterpret_cast<const int4*>(slots + j);

#define G8(ia, ib) { \
    unsigned u0 = *reinterpret_cast<const unsigned*>(&Xb[(size_t)(ia).x*D + c2]); \
    unsigned u1 = *reinterpret_cast<const unsigned*>(&Xb[(size_t)(ia).y*D + c2]); \
    unsigned u2 = *reinterpret_cast<const unsigned*>(&Xb[(size_t)(ia).z*D + c2]); \
    unsigned u3 = *reinterpret_cast<const unsigned*>(&Xb[(size_t)(ia).w*D + c2]); \
    unsigned u4 = *reinterpret_cast<const unsigned*>(&Xb[(size_t)(ib).x*D + c2]); \
    unsigned u5 = *reinterpret_cast<const unsigned*>(&Xb[(size_t)(ib).y*D + c2]); \
    unsigned u6 = *reinterpret_cast<const unsigned*>(&Xb[(size_t)(ib).z*D + c2]); \
    unsigned u7 = *reinterpret_cast<const unsigned*>(&Xb[(size_t)(ib).w*D + c2]); \
    sx0 += b2f((ushort)u0); sy0 += b2f((ushort)(u0>>16)); \
    sx1 += b2f((ushort)u1); sy1 += b2f((ushort)(u1>>16)); \
    sx2 += b2f((ushort)u2); sy2 += b2f((ushort)(u2>>16)); \
    sx3 += b2f((ushort)u3); sy3 += b2f((ushort)(u3>>16)); \
    sx0 += b2f((ushort)u4); sy0 += b2f((ushort)(u4>>16)); \
    sx1 += b2f((ushort)u5); sy1 += b2f((ushort)(u5>>16)); \
    sx2 += b2f((ushort)u6); sy2 += b2f((ushort)(u6>>16)); \
    sx3 += b2f((ushort)u7); sy3 += b2f((ushort)(u7>>16)); }

  int g = 0;
  if (nfull >= 2){
    int4 ia = sp[0], ib = sp[1];
    for (g = 2; g + 2 <= nfull; g += 2){
      int4 na = sp[g], nb = sp[g+1];
      G8(ia, ib);
      ia = na; ib = nb;
    }
    G8(ia, ib);
  }
  if (g < nfull){
    int4 ia = sp[g];
    unsigned u0 = *reinterpret_cast<const unsigned*>(&Xb[(size_t)ia.x*D + c2]);
    unsigned u1 = *reinterpret_cast<const unsigned*>(&Xb[(size_t)ia.y*D + c2]);
    unsigned u2 = *reinterpret_cast<const unsigned*>(&Xb[(size_t)ia.z*D + c2]);
    unsigned u3 = *reinterpret_cast<const unsigned*>(&Xb[(size_t)ia.w*D + c2]);
    sx0 += b2f((ushort)u0); sy0 += b2f((ushort)(u0>>16));
    sx1 += b2f((ushort)u1); sy1 += b2f((ushort)(u1>>16));
    sx2 += b2f((ushort)u2); sy2 += b2f((ushort)(u2>>16));
    sx3 += b2f((ushort)u3); sy3 += b2f((ushort)(u3>>16));
  }
  j += 4*nfull;
  for (; j < end; ++j){
    unsigned u = *reinterpret_cast<const unsigned*>(&Xb[(size_t)slots[j]*D + c2]);
    sx0 += b2f((ushort)u); sy0 += b2f((ushort)(u>>16));
  }
#undef G8
  float deg = (float)(end - beg);
  float rc = deg > 0.f ? 1.0f/deg : 0.f;
  unsigned o = (unsigned)f2b((sx0+sx1+sx2+sx3)*rc)
             | ((unsigned)f2b((sy0+sy1+sy2+sy3)*rc) << 16);
  *reinterpret_cast<unsigned*>(&meanb[(size_t)node*D + c2]) = o;
}

// ---------------- persistent pipelined MFMA GEMM: 128x128 tile, 64x64 waves ----------------
// KS=8: C = [A0 | A1] @ Wb^T + bias (K=256). KS=4: C = A0 @ Wb^T + bias (K=128).
// 4 waves (2x2), each wave owns a 64x64 output (4x4 fragment grid, acc=64 VGPR).
// Grid = 512 persistent blocks (2/CU, LDS 41KB); 4 named register load-sets give
// 4-step global->reg lookahead; raw s_barrier with lgkmcnt(0) only (counted vmcnt).
// vs R5's 64x128 tile: 8 LDS reads per 16 MFMAs (was 10/16) and half the barriers
// per output row.
template<int KS>
__global__ __launch_bounds__(256, 2) void k_mfma(
    const ushort* __restrict__ A0, const ushort* __restrict__ A1,
    const ushort* __restrict__ Wb, const float* __restrict__ bias,
    ushort* __restrict__ C, float* __restrict__ gS, float* __restrict__ gQ,
    int N, int NT)
{
  constexpr int KW = KS * 32;                // W row stride (K)
  __shared__ ushort At[2][128][40];
  __shared__ ushort Wt[2][128][40];
  __shared__ float shS[128], shQ[128];
  const int tid = threadIdx.x;
  if (tid < 128){ shS[tid]=0.f; shQ[tid]=0.f; }
  const int bid = blockIdx.x, gridN = gridDim.x;
  const int lane = tid & 63, wid = tid >> 6;
  const int wr = wid >> 1, wc = wid & 1;
  const int lr = lane & 15, kq = lane >> 4;
  const int sr = tid >> 2, s8 = (tid & 3) * 8;   // staging: rows sr and sr+64

  // 4 named register load-sets: each = 2 A int4 + 2 W int4
  int4 a0a,a0b, a1a,a1b, a2a,a2b, a3a,a3b;
  int4 w0a,w0b, w1a,w1b, w2a,w2b, w3a,w3b;

#define LOADSET(S, GT, TT) { \
    int gr0_ = (GT)*128 + sr;      if (gr0_ >= N) gr0_ = N-1; \
    int gr1_ = (GT)*128 + sr + 64; if (gr1_ >= N) gr1_ = N-1; \
    const ushort* As_ = (KS == 8 && (TT) >= 4) ? A1 : A0; \
    const int ka_ = ((TT) & 3) * 32; \
    a##S##a = *reinterpret_cast<const int4*>(&As_[(size_t)gr0_*D + ka_ + s8]); \
    a##S##b = *reinterpret_cast<const int4*>(&As_[(size_t)gr1_*D + ka_ + s8]); \
    w##S##a = *reinterpret_cast<const int4*>(&Wb[(size_t)sr*KW + (TT)*32 + s8]); \
    w##S##b = *reinterpret_cast<const int4*>(&Wb[(size_t)(sr+64)*KW + (TT)*32 + s8]); }

#define WRITESET(S, BW) { \
    *reinterpret_cast<int4*>(&At[BW][sr][s8]) = a##S##a; \
    *reinterpret_cast<int4*>(&At[BW][sr+64][s8]) = a##S##b; \
    *reinterpret_cast<int4*>(&Wt[BW][sr][s8]) = w##S##a; \
    *reinterpret_cast<int4*>(&Wt[BW][sr+64][s8]) = w##S##b; }

#define PBAR() { asm volatile("s_waitcnt lgkmcnt(0)" ::: "memory"); \
    __builtin_amdgcn_s_barrier(); __builtin_amdgcn_sched_barrier(0); }

#define STEPBODY(BR, ...) { \
    bf16x8 af0 = *reinterpret_cast<const bf16x8*>(&At[BR][64*wr + lr][kq*8]); \
    bf16x8 af1 = *reinterpret_cast<const bf16x8*>(&At[BR][64*wr + 16 + lr][kq*8]); \
    bf16x8 af2 = *reinterpret_cast<const bf16x8*>(&At[BR][64*wr + 32 + lr][kq*8]); \
    bf16x8 af3 = *reinterpret_cast<const bf16x8*>(&At[BR][64*wr + 48 + lr][kq*8]); \
    bf16x8 bw0 = *reinterpret_cast<const bf16x8*>(&Wt[BR][64*wc + lr][kq*8]); \
    bf16x8 bw1 = *reinterpret_cast<const bf16x8*>(&Wt[BR][64*wc + 16 + lr][kq*8]); \
    bf16x8 bw2 = *reinterpret_cast<const bf16x8*>(&Wt[BR][64*wc + 32 + lr][kq*8]); \
    bf16x8 bw3 = *reinterpret_cast<const bf16x8*>(&Wt[BR][64*wc + 48 + lr][kq*8]); \
    __VA_ARGS__; \
    acc[0][0] = __builtin_amdgcn_mfma_f32_16x16x32_bf16(af0, bw0, acc[0][0], 0,0,0); \
    acc[0][1] = __builtin_amdgcn_mfma_f32_16x16x32_bf16(af0, bw1, acc[0][1], 0,0,0); \
    acc[0][2] = __builtin_amdgcn_mfma_f32_16x16x32_bf16(af0, bw2, acc[0][2], 0,0,0); \
    acc[0][3] = __builtin_amdgcn_mfma_f32_16x16x32_bf16(af0, bw3, acc[0][3], 0,0,0); \
    acc[1][0] = __builtin_amdgcn_mfma_f32_16x16x32_bf16(af1, bw0, acc[1][0], 0,0,0); \
    acc[1][1] = __builtin_amdgcn_mfma_f32_16x16x32_bf16(af1, bw1, acc[1][1], 0,0,0); \
    acc[1][2] = __builtin_amdgcn_mfma_f32_16x16x32_bf16(af1, bw2, acc[1][2], 0,0,0); \
    acc[1][3] = __builtin_amdgcn_mfma_f32_16x16x32_bf16(af1, bw3, acc[1][3], 0,0,0); \
    acc[2][0] = __builtin_amdgcn_mfma_f32_16x16x32_bf16(af2, bw0, acc[2][0], 0,0,0); \
    acc[2][1] = __builtin_amdgcn_mfma_f32_16x16x32_bf16(af2, bw1, acc[2][1], 0,0,0); \
    acc[2][2] = __builtin_amdgcn_mfma_f32_16x16x32_bf16(af2, bw2, acc[2][2], 0,0,0); \
    acc[2][3] = __builtin_amdgcn_mfma_f32_16x16x32_bf16(af2, bw3, acc[2][3], 0,0,0); \
    acc[3][0] = __builtin_amdgcn_mfma_f32_16x16x32_bf16(af3, bw0, acc[3][0], 0,0,0); \
    acc[3][1] = __builtin_amdgcn_mfma_f32_16x16x32_bf16(af3, bw1, acc[3][1], 0,0,0); \
    acc[3][2] = __builtin_amdgcn_mfma_f32_16x16x32_bf16(af3, bw2, acc[3][2], 0,0,0); \
    acc[3][3] = __builtin_amdgcn_mfma_f32_16x16x32_bf16(af3, bw3, acc[3][3], 0,0,0); }

  f32x4 acc[4][4];
  #pragma unroll
  for (int m=0;m<4;m++)
    #pragma unroll
    for (int n=0;n<4;n++) acc[m][n] = (f32x4){0.f,0.f,0.f,0.f};
  float bs[4]={0,0,0,0}, bq[4]={0,0,0,0};
  float bv[4];
  #pragma unroll
  for (int n=0;n<4;n++) bv[n] = bias[64*wc + 16*n + lr];

  // prologue: prime 4 sets (k-steps 0..3 of first tile), stage step 0 into buf0
  {
    const int t0 = bid;
    LOADSET(0, t0, 0);
    LOADSET(1, t0, 1);
    LOADSET(2, t0, 2);
    LOADSET(3, t0, 3);
    WRITESET(0, 0);
    PBAR();
  }

  for (int tile = bid; tile < NT; tile += gridN){
    const int tnext = tile + gridN;
    const bool hasnext = (tnext < NT);
    if (KS == 8){
      STEPBODY(0, LOADSET(0, tile, 4));
      WRITESET(1, 1); PBAR();
      STEPBODY(1, LOADSET(1, tile, 5));
      WRITESET(2, 0); PBAR();
      STEPBODY(0, LOADSET(2, tile, 6));
      WRITESET(3, 1); PBAR();
      STEPBODY(1, LOADSET(3, tile, 7));
      WRITESET(0, 0); PBAR();
      STEPBODY(0, if (hasnext) LOADSET(0, tnext, 0));
      WRITESET(1, 1); PBAR();
      STEPBODY(1, if (hasnext) LOADSET(1, tnext, 1));
      WRITESET(2, 0); PBAR();
      STEPBODY(0, if (hasnext) LOADSET(2, tnext, 2));
      WRITESET(3, 1); PBAR();
      STEPBODY(1, if (hasnext) LOADSET(3, tnext, 3));
      if (hasnext){ WRITESET(0, 0); PBAR(); }
    } else {
      STEPBODY(0, if (hasnext) LOADSET(0, tnext, 0));
      WRITESET(1, 1); PBAR();
      STEPBODY(1, if (hasnext) LOADSET(1, tnext, 1));
      WRITESET(2, 0); PBAR();
      STEPBODY(0, if (hasnext) LOADSET(2, tnext, 2));
      WRITESET(3, 1); PBAR();
      STEPBODY(1, if (hasnext) LOADSET(3, tnext, 3));
      if (hasnext){ WRITESET(0, 0); PBAR(); }
    }

    // per-tile epilogue (stores overlap next tile's in-flight loads / ds_reads)
    #pragma unroll
    for (int m=0;m<4;m++){
      #pragma unroll
      for (int r=0;r<4;r++){
        int row = tile*128 + 64*wr + 16*m + kq*4 + r;
        if (row < N){
          #pragma unroll
          for (int n=0;n<4;n++){
            int col = 64*wc + 16*n + lr;
            float v = acc[m][n][r] + bv[n];
            C[(size_t)row*D + col] = f2b(v);
            bs[n] += v; bq[n] += v*v;
          }
        }
      }
    }
    #pragma unroll
    for (int m=0;m<4;m++)
      #pragma unroll
      for (int n=0;n<4;n++) acc[m][n] = (f32x4){0.f,0.f,0.f,0.f};
  }
#undef LOADSET
#undef WRITESET
#undef PBAR
#undef STEPBODY

  // one stat-reduction per block
  #pragma unroll
  for (int n=0;n<4;n++){
    float s = bs[n], q = bq[n];
    s += __shfl_xor(s,16); s += __shfl_xor(s,32);
    q += __shfl_xor(q,16); q += __shfl_xor(q,32);
    if (kq == 0){
      int col = 64*wc + 16*n + lr;
      atomicAdd(&shS[col], s);
      atomicAdd(&shQ[col], q);
    }
  }
  __syncthreads();
  if (tid < 128){
    unsafeAtomicAdd(&gS[tid], shS[tid]);
    unsafeAtomicAdd(&gQ[tid], shQ[tid]);
  }
}

// ---------------- BN finalize ----------------
__global__ void k_bnfin(const float* __restrict__ sum, const float* __restrict__ sq,
                        const float* __restrict__ g, const float* __restrict__ be,
                        float* __restrict__ bnA, float* __restrict__ bnB, float invN){
  int c = threadIdx.x;
  float m = sum[c]*invN;
  float v = sq[c]*invN - m*m;
  float a = g[c]*rsqrtf(fmaxf(v, 0.f) + 1e-5f);
  bnA[c] = a;
  bnB[c] = be[c] - m*a;
}

// ---------------- BN + ReLU, bf16 in -> bf16 out ----------------
__global__ __launch_bounds__(256) void k_bnrelub(const ushort* __restrict__ hpre,
      ushort* __restrict__ hb,
      const float* __restrict__ A, const float* __restrict__ Bp, long long n4){
  long long i = (long long)blockIdx.x*256 + threadIdx.x;
  const long long stride = (long long)gridDim.x*256;
  for (; i < n4; i += stride){
    int c = ((int)(i & 31)) << 2;
    float4 a = *reinterpret_cast<const float4*>(A + c);
    float4 b = *reinterpret_cast<const float4*>(Bp + c);
    ushort4 hv = reinterpret_cast<const ushort4*>(hpre)[i];
    ushort4 o;
    o.x = f2b(fmaxf(a.x*b2f(hv.x) + b.x, 0.f));
    o.y = f2b(fmaxf(a.y*b2f(hv.y) + b.y, 0.f));
    o.z = f2b(fmaxf(a.z*b2f(hv.z) + b.z, 0.f));
    o.w = f2b(fmaxf(a.w*b2f(hv.w) + b.w, 0.f));
    reinterpret_cast<ushort4*>(hb)[i] = o;
  }
}

// ---------------- final: out = relu(bn2(h2) + bn3(skip)), f32 out ----------------
__global__ __launch_bounds__(256) void k_final(const ushort* __restrict__ h2,
      const ushort* __restrict__ sk, float* __restrict__ out,
      const float* __restrict__ A2, const float* __restrict__ B2,
      const float* __restrict__ A3, const float* __restrict__ B3, long long n4){
  long long i = (long long)blockIdx.x*256 + threadIdx.x;
  const long long stride = (long long)gridDim.x*256;
  for (; i < n4; i += stride){
    int c = ((int)(i & 31)) << 2;
    float4 a2 = *reinterpret_cast<const float4*>(A2 + c);
    float4 b2 = *reinterpret_cast<const float4*>(B2 + c);
    float4 a3 = *reinterpret_cast<const float4*>(A3 + c);
    float4 b3 = *reinterpret_cast<const float4*>(B3 + c);
    ushort4 h = reinterpret_cast<const ushort4*>(h2)[i];
    ushort4 s = reinterpret_cast<const ushort4*>(sk)[i];
    float4 v;
    v.x = fmaxf(a2.x*b2f(h.x) + b2.x + a3.x*b2f(s.x) + b3.x, 0.f);
    v.y = fmaxf(a2.y*b2f(h.y) + b2.y + a3.y*b2f(s.y) + b3.y, 0.f);
    v.z = fmaxf(a2.z*b2f(h.z) + b2.z + a3.z*b2f(s.z) + b3.z, 0.f);
    v.w = fmaxf(a2.w*b2f(h.w) + b2.w + a3.w*b2f(s.w) + b3.w, 0.f);
    reinterpret_cast<float4*>(out)[i] = v;
  }
}

extern "C" void kernel_launch(void* const* d_in, const int* in_sizes, int n_in,
                              void* d_out, int out_size, void* d_ws, size_t ws_size,
                              hipStream_t stream) {
  const float* x        = (const float*)d_in[0];
  const int*   src      = (const int*)  d_in[1];
  const int*   dst      = (const int*)  d_in[2];
  const float* w_self1  = (const float*)d_in[3];
  const float* w_neigh1 = (const float*)d_in[4];
  const float* b1       = (const float*)d_in[5];
  const float* w_self2  = (const float*)d_in[6];
  const float* w_neigh2 = (const float*)d_in[7];
  const float* b2       = (const float*)d_in[8];
  const float* w_skip   = (const float*)d_in[9];
  const float* b_skip   = (const float*)d_in[10];
  const float* g1       = (const float*)d_in[11];
  const float* be1      = (const float*)d_in[12];
  const float* g2       = (const float*)d_in[13];
  const float* be2      = (const float*)d_in[14];
  const float* g3       = (const float*)d_in[15];
  const float* be3      = (const float*)d_in[16];
  (void)n_in; (void)ws_size;

  const int N = in_sizes[0] / D;
  const int E = in_sizes[1];
  const int NB = (N + 255) >> 8;
  float* out = (float*)d_out;

  // ---- workspace layout ----
  char* p = (char*)d_ws;
  const size_t nd2 = (((size_t)N * D * 2) + 255) / 256 * 256;   // bf16 [N][D]
  ushort* meanb  = (ushort*)p; p += nd2;
  ushort* h1b    = (ushort*)p; p += nd2;
  ushort* hpre_b = (ushort*)p; p += nd2;     // h1pre, then h2pre (aliased)
  ushort* skip_b = (ushort*)p; p += nd2;
  ushort* Wb1    = (ushort*)p; p += 256*128*2;
  ushort* Wb2    = (ushort*)p; p += 256*128*2;
  ushort* Wb3    = (ushort*)p; p += 128*128*2;
  int*    offs   = (int*)p;   p += (((size_t)(N+1)*4) + 255) / 256 * 256;
  int*    bcnt   = (int*)p;   p += 2304;
  float*  st     = (float*)p; p += 1536*sizeof(float);
  int*    bbase  = (int*)p;   p += 2304;
  int*    bcur   = (int*)p;   p += 2048;
  float *sum1=st,      *sq1=st+128,  *sum2=st+256, *sq2=st+384, *sum3=st+512, *sq3=st+640;
  float *bnA1=st+768,  *bnB1=st+896, *bnA2=st+1024,*bnB2=st+1152,*bnA3=st+1280,*bnB3=st+1408;

  // scratch in d_out (dead before k_final rewrites all of d_out)
  const size_t slpad = (((size_t)E*4) + 255) / 256 * 256;
  const size_t xbpad = (((size_t)N*D*2) + 255) / 256 * 256;
  int*      slots = (int*)d_out;
  ushort*   xb    = (ushort*)((char*)d_out + slpad);
  unsigned* pairs = (unsigned*)((char*)d_out + slpad + xbpad);

  hipMemsetAsync(bcnt, 0, 2304 + 1536*sizeof(float), stream);

  const long long n4 = (long long)N * D / 4;

  // --- casts / weight prep ---
  k_xcast<<<2048, 256, 0, stream>>>(x, xb, n4);
  k_wt<<<64, 256, 0, stream>>>(w_self1,  Wb1, 256, 0);
  k_wt<<<64, 256, 0, stream>>>(w_neigh1, Wb1, 256, 128);
  k_wt<<<64, 256, 0, stream>>>(w_self2,  Wb2, 256, 0);
  k_wt<<<64, 256, 0, stream>>>(w_neigh2, Wb2, 256, 128);
  k_wt<<<64, 256, 0, stream>>>(w_skip,   Wb3, 128, 0);

  // --- CSR build via 2-level counting sort ---
  k_p0<<<1024, 256, 0, stream>>>(dst, bcnt, E);
  k_bscan<<<1, 1024, 0, stream>>>(bcnt, bbase, bcur, NB, E);
  k_part<<<(E + PCHUNK - 1)/PCHUNK, 256, 0, stream>>>(src, dst, bcur, pairs, E);
  k_sortb<<<NB, 256, 0, stream>>>(pairs, bbase, offs, slots, N, NB);

  const int gablocks = (N + 3) / 4;
  const int NT = (N + 127) / 128;
  const int gpersist = 512;                 // 2 persistent blocks per CU
  const float invN = 1.0f / (float)N;

  // --- layer 1 ---
  k_gatherb<<<gablocks, 256, 0, stream>>>(xb, slots, offs, meanb, N);
  k_mfma<8><<<gpersist, 256, 0, stream>>>(xb, meanb, Wb1, b1, hpre_b, sum1, sq1, N, NT);
  k_bnfin<<<1, 128, 0, stream>>>(sum1, sq1, g1, be1, bnA1, bnB1, invN);
  k_bnrelub<<<4096, 256, 0, stream>>>(hpre_b, h1b, bnA1, bnB1, n4);

  // --- layer 2 aggregation ---
  k_gatherb<<<gablocks, 256, 0, stream>>>(h1b, slots, offs, meanb, N);

  // layer-2 main GEMM + separate persistent skip GEMM
  k_mfma<8><<<gpersist, 256, 0, stream>>>(h1b, meanb, Wb2, b2, hpre_b, sum2, sq2, N, NT);
  k_mfma<4><<<gpersist, 256, 0, stream>>>(h1b, nullptr, Wb3, b_skip, skip_b, sum3, sq3, N, NT);
  k_bnfin<<<1, 128, 0, stream>>>(sum2, sq2, g2, be2, bnA2, bnB2, invN);
  k_bnfin<<<1, 128, 0, stream>>>(sum3, sq3, g3, be3, bnA3, bnB3, invN);

  k_final<<<4096, 256, 0, stream>>>(hpre_b, skip_b, out, bnA2, bnB2, bnA3, bnB3, n4);
}

// Round 9
// 301.262 us; speedup vs baseline: 2.5504x; 1.0946x over previous
//
#include <hip/hip_runtime.h>

#define D 128
#define PCHUNK 4096
#define SCAP 8192

typedef short bf16x8 __attribute__((ext_vector_type(8)));
typedef float f32x4 __attribute__((ext_vector_type(4)));

__device__ __forceinline__ ushort f2b(float f){
  unsigned u = __builtin_bit_cast(unsigned, f);
  u += 0x7fffu + ((u >> 16) & 1u);          // round-to-nearest-even
  return (ushort)(u >> 16);
}
__device__ __forceinline__ float b2f(ushort h){
  unsigned u = ((unsigned)h) << 16;
  return __builtin_bit_cast(float, u);
}

// ---------------- P0: coarse bucket histogram (bucket = dst>>8) ----------------
__global__ __launch_bounds__(256) void k_p0(const int* __restrict__ dst,
                                            int* __restrict__ bcnt, int E){
  __shared__ int h[512];
  for (int u=threadIdx.x; u<512; u+=256) h[u]=0;
  __syncthreads();
  for (long long i=(long long)blockIdx.x*256+threadIdx.x; i<E; i+=(long long)gridDim.x*256)
    atomicAdd(&h[dst[i]>>8], 1);
  __syncthreads();
  for (int u=threadIdx.x; u<512; u+=256) if (h[u]) atomicAdd(&bcnt[u], h[u]);
}

// ---------------- P1: scan buckets -> base & cursor ----------------
__global__ void k_bscan(const int* __restrict__ bcnt, int* __restrict__ bbase,
                        int* __restrict__ bcur, int nb, int E){
  __shared__ int sh[1024];
  int t = threadIdx.x;
  int v = (t<nb) ? bcnt[t] : 0;
  sh[t]=v; __syncthreads();
  for (int off=1; off<1024; off<<=1){
    int add = (t>=off)?sh[t-off]:0;
    __syncthreads();
    sh[t]+=add;
    __syncthreads();
  }
  if (t<nb){ int e=sh[t]-v; bbase[t]=e; bcur[t]=e; }
  if (t==nb) bbase[t]=E;
}

// ---------------- P2: LDS-binned partition; pairs packed as src | (dst&255)<<24 ------
__global__ __launch_bounds__(256) void k_part(const int* __restrict__ src,
        const int* __restrict__ dst, int* __restrict__ bcur,
        unsigned* __restrict__ pairs, int E){
  __shared__ int hist[512], offA[512], offB[512], gbase[512];
  __shared__ int sS[PCHUNK], sD[PCHUNK];
  const int t = threadIdx.x;
  const int base = blockIdx.x * PCHUNK;
  const int cnt = min(PCHUNK, E - base);
  for (int u=t; u<512; u+=256) hist[u]=0;
  __syncthreads();
  int rs[16], rd[16];
  #pragma unroll
  for (int j=0;j<16;j++){
    int li = j*256 + t;
    if (li < cnt){
      rs[j]=src[base+li]; rd[j]=dst[base+li];
      atomicAdd(&hist[rd[j]>>8],1);
    } else { rs[j]=0; rd[j]=-1; }
  }
  __syncthreads();
  int *cur=offA, *nxt=offB;
  for (int u=t; u<512; u+=256) cur[u]=hist[u];
  __syncthreads();
  for (int off=1; off<512; off<<=1){
    for (int u=t; u<512; u+=256) nxt[u] = cur[u] + ((u>=off)?cur[u-off]:0);
    __syncthreads();
    int* tmp=cur; cur=nxt; nxt=tmp;
  }
  for (int u=t; u<512; u+=256) nxt[u] = cur[u]-hist[u];
  __syncthreads();
  #pragma unroll
  for (int j=0;j<16;j++){
    if (j*256+t < cnt){
      int b = rd[j]>>8;
      int p = atomicAdd(&nxt[b],1);
      sS[p]=rs[j]; sD[p]=rd[j];
    }
  }
  __syncthreads();
  for (int u=t; u<512; u+=256){
    int c = hist[u];
    if (c>0) gbase[u] = atomicAdd(&bcur[u], c);
  }
  __syncthreads();
  #pragma unroll
  for (int j=0;j<16;j++){
    int idx = j*256+t;
    if (idx<cnt){
      int d = sD[idx]; int b = d>>8;
      int gpos = gbase[b] + (idx - (cur[b]-hist[b]));
      pairs[gpos] = (unsigned)sS[idx] | ((unsigned)(d & 255) << 24);
    }
  }
}

// ---------------- P3: per-bucket exact counting sort -> slots + offs ----------------
__global__ __launch_bounds__(256) void k_sortb(const unsigned* __restrict__ pairs,
        const int* __restrict__ bbase, int* __restrict__ offs,
        int* __restrict__ slots, int N, int NB){
  __shared__ int nh[256], nc[256], sc[256];
  __shared__ int stage[SCAP];
  const int b = blockIdx.x, t = threadIdx.x;
  const int base = bbase[b];
  const int cnt  = bbase[b+1] - base;
  nh[t]=0; __syncthreads();
  for (int i=t;i<cnt;i+=256) atomicAdd(&nh[pairs[base+i] >> 24],1);
  __syncthreads();
  int v = nh[t];
  sc[t]=v; __syncthreads();
  for (int off=1; off<256; off<<=1){
    int add = (t>=off)?sc[t-off]:0;
    __syncthreads();
    sc[t]+=add;
    __syncthreads();
  }
  int excl = sc[t]-v;
  nc[t]=excl;
  int node = (b<<8)+t;
  if (node<N) offs[node]=base+excl;
  if (b==NB-1 && t==0) offs[N]=bbase[NB];
  __syncthreads();
  if (cnt<=SCAP){
    for (int i=t;i<cnt;i+=256){
      unsigned p = pairs[base+i];
      int pos = atomicAdd(&nc[p >> 24],1);
      stage[pos]=(int)(p & 0xffffffu);
    }
    __syncthreads();
    for (int i=t;i<cnt;i+=256) slots[base+i]=stage[i];
  } else {
    for (int i=t;i<cnt;i+=256){
      unsigned p = pairs[base+i];
      int pos = atomicAdd(&nc[p >> 24],1);
      slots[base+pos]=(int)(p & 0xffffffu);
    }
  }
}

// ---------------- f32 -> bf16 cast ----------------
__global__ __launch_bounds__(256) void k_xcast(const float* __restrict__ x,
                                               ushort* __restrict__ xb, long long n4){
  long long i = (long long)blockIdx.x*256 + threadIdx.x;
  const long long stride = (long long)gridDim.x*256;
  for (; i < n4; i += stride){
    float4 v = reinterpret_cast<const float4*>(x)[i];
    ushort4 o;
    o.x = f2b(v.x); o.y = f2b(v.y); o.z = f2b(v.z); o.w = f2b(v.w);
    reinterpret_cast<ushort4*>(xb)[i] = o;
  }
}

// ---------------- all weight transposes in ONE launch ----------------
// blocks [0,64):   w_self1  -> Wb1 (K=256, k0=0)
// blocks [64,128): w_neigh1 -> Wb1 (K=256, k0=128)
// blocks [128,192):w_self2  -> Wb2 (K=256, k0=0)
// blocks [192,256):w_neigh2 -> Wb2 (K=256, k0=128)
// blocks [256,320):w_skip   -> Wb3 (K=128, k0=0)
__global__ __launch_bounds__(256) void k_wtall(
    const float* __restrict__ w_self1, const float* __restrict__ w_neigh1,
    const float* __restrict__ w_self2, const float* __restrict__ w_neigh2,
    const float* __restrict__ w_skip,
    ushort* __restrict__ Wb1, ushort* __restrict__ Wb2, ushort* __restrict__ Wb3){
  const int grp = blockIdx.x >> 6;            // 0..4
  const int idx = (blockIdx.x & 63)*256 + threadIdx.x;  // 0..16383
  const int k = idx >> 7, c = idx & 127;
  const float* W; ushort* Wb; int K, k0;
  switch (grp){
    case 0: W=w_self1;  Wb=Wb1; K=256; k0=0;   break;
    case 1: W=w_neigh1; Wb=Wb1; K=256; k0=128; break;
    case 2: W=w_self2;  Wb=Wb2; K=256; k0=0;   break;
    case 3: W=w_neigh2; Wb=Wb2; K=256; k0=128; break;
    default:W=w_skip;   Wb=Wb3; K=128; k0=0;   break;
  }
  Wb[(size_t)c*K + k0 + k] = f2b(W[idx]);
}

// ---------------- gather-mean (bf16 in/out): 64 threads/node, pipelined 8-edge groups ----
// (R5 version — best measured: 67.7 us, 177 MB fetch; random-fill-bound floor)
__global__ __launch_bounds__(256) void k_gatherb(const ushort* __restrict__ Xb,
        const int* __restrict__ slots, const int* __restrict__ offs,
        ushort* __restrict__ meanb, int N){
  int node = blockIdx.x*4 + (threadIdx.x >> 6);
  int c2 = (threadIdx.x & 63) * 2;            // this lane's channel pair
  if (node >= N) return;
  const int beg = offs[node], end = offs[node+1];
  float sx0=0,sy0=0,sx1=0,sy1=0,sx2=0,sy2=0,sx3=0,sy3=0;
  int j = beg;
  while (j < end && (j & 3)){
    unsigned u = *reinterpret_cast<const unsigned*>(&Xb[(size_t)slots[j]*D + c2]);
    sx0 += b2f((ushort)u); sy0 += b2f((ushort)(u>>16));
    ++j;
  }
  const int nfull = (end - j) >> 2;
  const int4* sp = reinterpret_cast<const int4*>(slots + j);

#define G8(ia, ib) { \
    unsigned u0 = *reinterpret_cast<const unsigned*>(&Xb[(size_t)(ia).x*D + c2]); \
    unsigned u1 = *reinterpret_cast<const unsigned*>(&Xb[(size_t)(ia).y*D + c2]); \
    unsigned u2 = *reinterpret_cast<const unsigned*>(&Xb[(size_t)(ia).z*D + c2]); \
    unsigned u3 = *reinterpret_cast<const unsigned*>(&Xb[(size_t)(ia).w*D + c2]); \
    unsigned u4 = *reinterpret_cast<const unsigned*>(&Xb[(size_t)(ib).x*D + c2]); \
    unsigned u5 = *reinterpret_cast<const unsigned*>(&Xb[(size_t)(ib).y*D + c2]); \
    unsigned u6 = *reinterpret_cast<const unsigned*>(&Xb[(size_t)(ib).z*D + c2]); \
    unsigned u7 = *reinterpret_cast<const unsigned*>(&Xb[(size_t)(ib).w*D + c2]); \
    sx0 += b2f((ushort)u0); sy0 += b2f((ushort)(u0>>16)); \
    sx1 += b2f((ushort)u1); sy1 += b2f((ushort)(u1>>16)); \
    sx2 += b2f((ushort)u2); sy2 += b2f((ushort)(u2>>16)); \
    sx3 += b2f((ushort)u3); sy3 += b2f((ushort)(u3>>16)); \
    sx0 += b2f((ushort)u4); sy0 += b2f((ushort)(u4>>16)); \
    sx1 += b2f((ushort)u5); sy1 += b2f((ushort)(u5>>16)); \
    sx2 += b2f((ushort)u6); sy2 += b2f((ushort)(u6>>16)); \
    sx3 += b2f((ushort)u7); sy3 += b2f((ushort)(u7>>16)); }

  int g = 0;
  if (nfull >= 2){
    int4 ia = sp[0], ib = sp[1];
    for (g = 2; g + 2 <= nfull; g += 2){
      int4 na = sp[g], nb = sp[g+1];
      G8(ia, ib);
      ia = na; ib = nb;
    }
    G8(ia, ib);
  }
  if (g < nfull){
    int4 ia = sp[g];
    unsigned u0 = *reinterpret_cast<const unsigned*>(&Xb[(size_t)ia.x*D + c2]);
    unsigned u1 = *reinterpret_cast<const unsigned*>(&Xb[(size_t)ia.y*D + c2]);
    unsigned u2 = *reinterpret_cast<const unsigned*>(&Xb[(size_t)ia.z*D + c2]);
    unsigned u3 = *reinterpret_cast<const unsigned*>(&Xb[(size_t)ia.w*D + c2]);
    sx0 += b2f((ushort)u0); sy0 += b2f((ushort)(u0>>16));
    sx1 += b2f((ushort)u1); sy1 += b2f((ushort)(u1>>16));
    sx2 += b2f((ushort)u2); sy2 += b2f((ushort)(u2>>16));
    sx3 += b2f((ushort)u3); sy3 += b2f((ushort)(u3>>16));
  }
  j += 4*nfull;
  for (; j < end; ++j){
    unsigned u = *reinterpret_cast<const unsigned*>(&Xb[(size_t)slots[j]*D + c2]);
    sx0 += b2f((ushort)u); sy0 += b2f((ushort)(u>>16));
  }
#undef G8
  float deg = (float)(end - beg);
  float rc = deg > 0.f ? 1.0f/deg : 0.f;
  unsigned o = (unsigned)f2b((sx0+sx1+sx2+sx3)*rc)
             | ((unsigned)f2b((sy0+sy1+sy2+sy3)*rc) << 16);
  *reinterpret_cast<unsigned*>(&meanb[(size_t)node*D + c2]) = o;
}

// ---------------- persistent 2-phase pipelined MFMA GEMM, 4-deep lookahead (R5) --------
// 64x128 tile, 4 waves (2x2). C = [A0 | A1] @ Wb^T + bias (K=256),
// optional fused skip Ck = A0 @ Wk^T + biasK (K=128).
// Grid = 512 persistent blocks (2/CU); pipeline never drains across tiles.
// + T5: s_setprio(1) around the MFMA cluster (role-split waves exist: loads vs MFMA).
template<bool SKIP>
__global__ __launch_bounds__(256, 2) void k_mfma(
    const ushort* __restrict__ A0, const ushort* __restrict__ A1,
    const ushort* __restrict__ Wb, const ushort* __restrict__ Wk,
    const float* __restrict__ bias, const float* __restrict__ biasK,
    ushort* __restrict__ C, ushort* __restrict__ Ck,
    float* __restrict__ gS, float* __restrict__ gQ,
    float* __restrict__ gSK, float* __restrict__ gQK, int N, int NT)
{
  __shared__ ushort At[2][64][40];
  __shared__ ushort Wt[2][128][40];
  __shared__ ushort Wkt[SKIP ? 2*128*40 : 1];
  __shared__ float shS[128], shQ[128], shSK[SKIP?128:1], shQK[SKIP?128:1];
  const int tid = threadIdx.x;
  if (tid < 128){ shS[tid]=0.f; shQ[tid]=0.f; if (SKIP){ shSK[tid]=0.f; shQK[tid]=0.f; } }
  const int bid = blockIdx.x, gridN = gridDim.x;
  const int lane = tid & 63, wid = tid >> 6;
  const int wr = wid >> 1, wc = wid & 1;
  const int lr = lane & 15, kq = lane >> 4;
  const int srA = tid >> 2, s8A = (tid & 3) * 8;
  const int srW = tid >> 2, s8W = (tid & 3) * 8;

  // 4 named register load-sets (period 4 divides the 8-step tile -> static naming)
  int4 va0, va1, va2, va3;
  int4 w0a,w0b, w1a,w1b, w2a,w2b, w3a,w3b;
  int4 k0a,k0b, k1a,k1b, k2a,k2b, k3a,k3b;

#define LOADSET(S, GT, TT) { \
    int grow_ = (GT)*64 + srA; if (grow_ >= N) grow_ = N-1; \
    const ushort* As_ = ((TT) >= 4) ? A1 : A0; \
    va##S = *reinterpret_cast<const int4*>(&As_[(size_t)grow_*D + ((TT)&3)*32 + s8A]); \
    w##S##a = *reinterpret_cast<const int4*>(&Wb[(size_t)srW*256 + (TT)*32 + s8W]); \
    w##S##b = *reinterpret_cast<const int4*>(&Wb[(size_t)(srW+64)*256 + (TT)*32 + s8W]); \
    if (SKIP && (TT) < 4){ \
      k##S##a = *reinterpret_cast<const int4*>(&Wk[(size_t)srW*128 + (TT)*32 + s8W]); \
      k##S##b = *reinterpret_cast<const int4*>(&Wk[(size_t)(srW+64)*128 + (TT)*32 + s8W]); \
    } }

#define WRITESET(S, BW, TT) { \
    *reinterpret_cast<int4*>(&At[BW][srA][s8A]) = va##S; \
    *reinterpret_cast<int4*>(&Wt[BW][srW][s8W]) = w##S##a; \
    *reinterpret_cast<int4*>(&Wt[BW][srW+64][s8W]) = w##S##b; \
    if (SKIP && (TT) < 4){ \
      *reinterpret_cast<int4*>(&Wkt[((BW)*128 + srW)*40 + s8W]) = k##S##a; \
      *reinterpret_cast<int4*>(&Wkt[((BW)*128 + srW + 64)*40 + s8W]) = k##S##b; \
    } }

#define PBAR() { asm volatile("s_waitcnt lgkmcnt(0)" ::: "memory"); \
    __builtin_amdgcn_s_barrier(); __builtin_amdgcn_sched_barrier(0); }

#define STEPBODY(BR, WITHK, ...) { \
    bf16x8 af0 = *reinterpret_cast<const bf16x8*>(&At[BR][32*wr + lr][kq*8]); \
    bf16x8 af1 = *reinterpret_cast<const bf16x8*>(&At[BR][32*wr + 16 + lr][kq*8]); \
    bf16x8 bw0 = *reinterpret_cast<const bf16x8*>(&Wt[BR][64*wc + lr][kq*8]); \
    bf16x8 bw1 = *reinterpret_cast<const bf16x8*>(&Wt[BR][64*wc + 16 + lr][kq*8]); \
    bf16x8 bw2 = *reinterpret_cast<const bf16x8*>(&Wt[BR][64*wc + 32 + lr][kq*8]); \
    bf16x8 bw3 = *reinterpret_cast<const bf16x8*>(&Wt[BR][64*wc + 48 + lr][kq*8]); \
    bf16x8 bk0{}, bk1{}, bk2{}, bk3{}; \
    if (SKIP && (WITHK)){ \
      bk0 = *reinterpret_cast<const bf16x8*>(&Wkt[((BR)*128 + 64*wc + lr)*40 + kq*8]); \
      bk1 = *reinterpret_cast<const bf16x8*>(&Wkt[((BR)*128 + 64*wc + 16 + lr)*40 + kq*8]); \
      bk2 = *reinterpret_cast<const bf16x8*>(&Wkt[((BR)*128 + 64*wc + 32 + lr)*40 + kq*8]); \
      bk3 = *reinterpret_cast<const bf16x8*>(&Wkt[((BR)*128 + 64*wc + 48 + lr)*40 + kq*8]); \
    } \
    __VA_ARGS__; \
    __builtin_amdgcn_s_setprio(1); \
    acc[0][0] = __builtin_amdgcn_mfma_f32_16x16x32_bf16(af0, bw0, acc[0][0], 0,0,0); \
    acc[0][1] = __builtin_amdgcn_mfma_f32_16x16x32_bf16(af0, bw1, acc[0][1], 0,0,0); \
    acc[0][2] = __builtin_amdgcn_mfma_f32_16x16x32_bf16(af0, bw2, acc[0][2], 0,0,0); \
    acc[0][3] = __builtin_amdgcn_mfma_f32_16x16x32_bf16(af0, bw3, acc[0][3], 0,0,0); \
    acc[1][0] = __builtin_amdgcn_mfma_f32_16x16x32_bf16(af1, bw0, acc[1][0], 0,0,0); \
    acc[1][1] = __builtin_amdgcn_mfma_f32_16x16x32_bf16(af1, bw1, acc[1][1], 0,0,0); \
    acc[1][2] = __builtin_amdgcn_mfma_f32_16x16x32_bf16(af1, bw2, acc[1][2], 0,0,0); \
    acc[1][3] = __builtin_amdgcn_mfma_f32_16x16x32_bf16(af1, bw3, acc[1][3], 0,0,0); \
    if (SKIP && (WITHK)){ \
      accK[0][0] = __builtin_amdgcn_mfma_f32_16x16x32_bf16(af0, bk0, accK[0][0], 0,0,0); \
      accK[0][1] = __builtin_amdgcn_mfma_f32_16x16x32_bf16(af0, bk1, accK[0][1], 0,0,0); \
      accK[0][2] = __builtin_amdgcn_mfma_f32_16x16x32_bf16(af0, bk2, accK[0][2], 0,0,0); \
      accK[0][3] = __builtin_amdgcn_mfma_f32_16x16x32_bf16(af0, bk3, accK[0][3], 0,0,0); \
      accK[1][0] = __builtin_amdgcn_mfma_f32_16x16x32_bf16(af1, bk0, accK[1][0], 0,0,0); \
      accK[1][1] = __builtin_amdgcn_mfma_f32_16x16x32_bf16(af1, bk1, accK[1][1], 0,0,0); \
      accK[1][2] = __builtin_amdgcn_mfma_f32_16x16x32_bf16(af1, bk2, accK[1][2], 0,0,0); \
      accK[1][3] = __builtin_amdgcn_mfma_f32_16x16x32_bf16(af1, bk3, accK[1][3], 0,0,0); \
    } \
    __builtin_amdgcn_s_setprio(0); }

  f32x4 acc[2][4], accK[SKIP?2:1][SKIP?4:1];
  #pragma unroll
  for (int m=0;m<2;m++)
    #pragma unroll
    for (int n=0;n<4;n++){
      acc[m][n] = (f32x4){0.f,0.f,0.f,0.f};
      if (SKIP) accK[m][n] = (f32x4){0.f,0.f,0.f,0.f};
    }
  float bs[4]={0,0,0,0}, bq[4]={0,0,0,0}, bsk[4]={0,0,0,0}, bqk[4]={0,0,0,0};
  float bv[4], bkv[4];
  #pragma unroll
  for (int n=0;n<4;n++){
    bv[n] = bias[64*wc + 16*n + lr];
    bkv[n] = SKIP ? biasK[64*wc + 16*n + lr] : 0.f;
  }

  // prologue: prime 4 sets (steps 0..3 of first tile), stage step 0 into buf0
  {
    const int t0 = bid;
    LOADSET(0, t0, 0);
    LOADSET(1, t0, 1);
    LOADSET(2, t0, 2);
    LOADSET(3, t0, 3);
    WRITESET(0, 0, 0);
    PBAR();
  }

  for (int tile = bid; tile < NT; tile += gridN){
    const int tnext = tile + gridN;
    const bool hasnext = (tnext < NT);
    STEPBODY(0, 1, LOADSET(0, tile, 4));
    WRITESET(1, 1, 1); PBAR();
    STEPBODY(1, 1, LOADSET(1, tile, 5));
    WRITESET(2, 0, 2); PBAR();
    STEPBODY(0, 1, LOADSET(2, tile, 6));
    WRITESET(3, 1, 3); PBAR();
    STEPBODY(1, 1, LOADSET(3, tile, 7));
    WRITESET(0, 0, 4); PBAR();
    STEPBODY(0, 0, if (hasnext) LOADSET(0, tnext, 0));
    WRITESET(1, 1, 5); PBAR();
    STEPBODY(1, 0, if (hasnext) LOADSET(1, tnext, 1));
    WRITESET(2, 0, 6); PBAR();
    STEPBODY(0, 0, if (hasnext) LOADSET(2, tnext, 2));
    WRITESET(3, 1, 7); PBAR();
    STEPBODY(1, 0, if (hasnext) LOADSET(3, tnext, 3));
    if (hasnext){ WRITESET(0, 0, 0); PBAR(); }

    // per-tile epilogue (stores overlap next tile's in-flight loads / ds_reads)
    #pragma unroll
    for (int m=0;m<2;m++){
      #pragma unroll
      for (int r=0;r<4;r++){
        int row = tile*64 + 32*wr + 16*m + kq*4 + r;
        if (row < N){
          #pragma unroll
          for (int n=0;n<4;n++){
            int col = 64*wc + 16*n + lr;
            float v = acc[m][n][r] + bv[n];
            C[(size_t)row*D + col] = f2b(v);
            bs[n] += v; bq[n] += v*v;
            if (SKIP){
              float u = accK[m][n][r] + bkv[n];
              Ck[(size_t)row*D + col] = f2b(u);
              bsk[n] += u; bqk[n] += u*u;
            }
          }
        }
      }
    }
    #pragma unroll
    for (int m=0;m<2;m++)
      #pragma unroll
      for (int n=0;n<4;n++){
        acc[m][n] = (f32x4){0.f,0.f,0.f,0.f};
        if (SKIP) accK[m][n] = (f32x4){0.f,0.f,0.f,0.f};
      }
  }
#undef LOADSET
#undef WRITESET
#undef PBAR
#undef STEPBODY

  // one stat-reduction per block
  #pragma unroll
  for (int n=0;n<4;n++){
    float s = bs[n], q = bq[n];
    s += __shfl_xor(s,16); s += __shfl_xor(s,32);
    q += __shfl_xor(q,16); q += __shfl_xor(q,32);
    if (kq == 0){
      int col = 64*wc + 16*n + lr;
      atomicAdd(&shS[col], s);
      atomicAdd(&shQ[col], q);
    }
    if (SKIP){
      float sk = bsk[n], qk = bqk[n];
      sk += __shfl_xor(sk,16); sk += __shfl_xor(sk,32);
      qk += __shfl_xor(qk,16); qk += __shfl_xor(qk,32);
      if (kq == 0){
        int col = 64*wc + 16*n + lr;
        atomicAdd(&shSK[col], sk);
        atomicAdd(&shQK[col], qk);
      }
    }
  }
  __syncthreads();
  if (tid < 128){
    unsafeAtomicAdd(&gS[tid], shS[tid]);
    unsafeAtomicAdd(&gQ[tid], shQ[tid]);
    if (SKIP){
      unsafeAtomicAdd(&gSK[tid], shSK[tid]);
      unsafeAtomicAdd(&gQK[tid], shQK[tid]);
    }
  }
}

// ---------------- BN + ReLU, bf16 in -> bf16 out (BN affine computed in-block) --------
__global__ __launch_bounds__(256) void k_bnrelub(const ushort* __restrict__ hpre,
      ushort* __restrict__ hb,
      const float* __restrict__ sum, const float* __restrict__ sq,
      const float* __restrict__ g, const float* __restrict__ be,
      float invN, long long n4){
  __shared__ float A[128], B[128];
  if (threadIdx.x < 128){
    int c = threadIdx.x;
    float m = sum[c]*invN;
    float v = sq[c]*invN - m*m;
    float a = g[c]*rsqrtf(fmaxf(v, 0.f) + 1e-5f);
    A[c] = a;
    B[c] = be[c] - m*a;
  }
  __syncthreads();
  long long i = (long long)blockIdx.x*256 + threadIdx.x;
  const long long stride = (long long)gridDim.x*256;
  for (; i < n4; i += stride){
    int c = ((int)(i & 31)) << 2;
    float4 a = *reinterpret_cast<const float4*>(A + c);
    float4 b = *reinterpret_cast<const float4*>(B + c);
    ushort4 hv = reinterpret_cast<const ushort4*>(hpre)[i];
    ushort4 o;
    o.x = f2b(fmaxf(a.x*b2f(hv.x) + b.x, 0.f));
    o.y = f2b(fmaxf(a.y*b2f(hv.y) + b.y, 0.f));
    o.z = f2b(fmaxf(a.z*b2f(hv.z) + b.z, 0.f));
    o.w = f2b(fmaxf(a.w*b2f(hv.w) + b.w, 0.f));
    reinterpret_cast<ushort4*>(hb)[i] = o;
  }
}

// ---------------- final: out = relu(bn2(h2) + bn3(skip)), f32 out (BN in-block) -------
__global__ __launch_bounds__(256) void k_final(const ushort* __restrict__ h2,
      const ushort* __restrict__ sk, float* __restrict__ out,
      const float* __restrict__ sum2, const float* __restrict__ sq2,
      const float* __restrict__ g2, const float* __restrict__ be2,
      const float* __restrict__ sum3, const float* __restrict__ sq3,
      const float* __restrict__ g3, const float* __restrict__ be3,
      float invN, long long n4){
  __shared__ float A2[128], B2[128], A3[128], B3[128];
  if (threadIdx.x < 128){
    int c = threadIdx.x;
    float m2 = sum2[c]*invN;
    float v2 = sq2[c]*invN - m2*m2;
    float a2 = g2[c]*rsqrtf(fmaxf(v2, 0.f) + 1e-5f);
    A2[c] = a2; B2[c] = be2[c] - m2*a2;
    float m3 = sum3[c]*invN;
    float v3 = sq3[c]*invN - m3*m3;
    float a3 = g3[c]*rsqrtf(fmaxf(v3, 0.f) + 1e-5f);
    A3[c] = a3; B3[c] = be3[c] - m3*a3;
  }
  __syncthreads();
  long long i = (long long)blockIdx.x*256 + threadIdx.x;
  const long long stride = (long long)gridDim.x*256;
  for (; i < n4; i += stride){
    int c = ((int)(i & 31)) << 2;
    float4 a2 = *reinterpret_cast<const float4*>(A2 + c);
    float4 b2 = *reinterpret_cast<const float4*>(B2 + c);
    float4 a3 = *reinterpret_cast<const float4*>(A3 + c);
    float4 b3 = *reinterpret_cast<const float4*>(B3 + c);
    ushort4 h = reinterpret_cast<const ushort4*>(h2)[i];
    ushort4 s = reinterpret_cast<const ushort4*>(sk)[i];
    float4 v;
    v.x = fmaxf(a2.x*b2f(h.x) + b2.x + a3.x*b2f(s.x) + b3.x, 0.f);
    v.y = fmaxf(a2.y*b2f(h.y) + b2.y + a3.y*b2f(s.y) + b3.y, 0.f);
    v.z = fmaxf(a2.z*b2f(h.z) + b2.z + a3.z*b2f(s.z) + b3.z, 0.f);
    v.w = fmaxf(a2.w*b2f(h.w) + b2.w + a3.w*b2f(s.w) + b3.w, 0.f);
    reinterpret_cast<float4*>(out)[i] = v;
  }
}

extern "C" void kernel_launch(void* const* d_in, const int* in_sizes, int n_in,
                              void* d_out, int out_size, void* d_ws, size_t ws_size,
                              hipStream_t stream) {
  const float* x        = (const float*)d_in[0];
  const int*   src      = (const int*)  d_in[1];
  const int*   dst      = (const int*)  d_in[2];
  const float* w_self1  = (const float*)d_in[3];
  const float* w_neigh1 = (const float*)d_in[4];
  const float* b1       = (const float*)d_in[5];
  const float* w_self2  = (const float*)d_in[6];
  const float* w_neigh2 = (const float*)d_in[7];
  const float* b2       = (const float*)d_in[8];
  const float* w_skip   = (const float*)d_in[9];
  const float* b_skip   = (const float*)d_in[10];
  const float* g1       = (const float*)d_in[11];
  const float* be1      = (const float*)d_in[12];
  const float* g2       = (const float*)d_in[13];
  const float* be2      = (const float*)d_in[14];
  const float* g3       = (const float*)d_in[15];
  const float* be3      = (const float*)d_in[16];
  (void)n_in; (void)ws_size;

  const int N = in_sizes[0] / D;
  const int E = in_sizes[1];
  const int NB = (N + 255) >> 8;
  float* out = (float*)d_out;

  // ---- workspace layout ----
  char* p = (char*)d_ws;
  const size_t nd2 = (((size_t)N * D * 2) + 255) / 256 * 256;   // bf16 [N][D]
  ushort* meanb  = (ushort*)p; p += nd2;
  ushort* h1b    = (ushort*)p; p += nd2;
  ushort* hpre_b = (ushort*)p; p += nd2;     // h1pre, then h2pre (aliased)
  ushort* skip_b = (ushort*)p; p += nd2;
  ushort* Wb1    = (ushort*)p; p += 256*128*2;
  ushort* Wb2    = (ushort*)p; p += 256*128*2;
  ushort* Wb3    = (ushort*)p; p += 128*128*2;
  int*    offs   = (int*)p;   p += (((size_t)(N+1)*4) + 255) / 256 * 256;
  int*    bcnt   = (int*)p;   p += 2304;
  float*  st     = (float*)p; p += 1536*sizeof(float);
  int*    bbase  = (int*)p;   p += 2304;
  int*    bcur   = (int*)p;   p += 2048;
  float *sum1=st,      *sq1=st+128,  *sum2=st+256, *sq2=st+384, *sum3=st+512, *sq3=st+640;

  // scratch in d_out (dead before k_final rewrites all of d_out)
  const size_t slpad = (((size_t)E*4) + 255) / 256 * 256;
  const size_t xbpad = (((size_t)N*D*2) + 255) / 256 * 256;
  int*      slots = (int*)d_out;
  ushort*   xb    = (ushort*)((char*)d_out + slpad);
  unsigned* pairs = (unsigned*)((char*)d_out + slpad + xbpad);

  hipMemsetAsync(bcnt, 0, 2304 + 1536*sizeof(float), stream);

  const long long n4 = (long long)N * D / 4;

  // --- casts / weight prep (one launch for all 5 transposes) ---
  k_xcast<<<2048, 256, 0, stream>>>(x, xb, n4);
  k_wtall<<<320, 256, 0, stream>>>(w_self1, w_neigh1, w_self2, w_neigh2, w_skip,
                                   Wb1, Wb2, Wb3);

  // --- CSR build via 2-level counting sort ---
  k_p0<<<1024, 256, 0, stream>>>(dst, bcnt, E);
  k_bscan<<<1, 1024, 0, stream>>>(bcnt, bbase, bcur, NB, E);
  k_part<<<(E + PCHUNK - 1)/PCHUNK, 256, 0, stream>>>(src, dst, bcur, pairs, E);
  k_sortb<<<NB, 256, 0, stream>>>(pairs, bbase, offs, slots, N, NB);

  const int gablocks = (N + 3) / 4;
  const int NT = (N + 63) / 64;
  const int gpersist = 512;                 // 2 persistent blocks per CU
  const float invN = 1.0f / (float)N;

  // --- layer 1 ---
  k_gatherb<<<gablocks, 256, 0, stream>>>(xb, slots, offs, meanb, N);
  k_mfma<false><<<gpersist, 256, 0, stream>>>(xb, meanb, Wb1, nullptr, b1, nullptr,
                                              hpre_b, nullptr, sum1, sq1, nullptr, nullptr, N, NT);
  k_bnrelub<<<4096, 256, 0, stream>>>(hpre_b, h1b, sum1, sq1, g1, be1, invN, n4);

  // --- layer 2 aggregation ---
  k_gatherb<<<gablocks, 256, 0, stream>>>(h1b, slots, offs, meanb, N);

  // fused layer-2 + skip GEMM (shares A fragments; h1b read once)
  k_mfma<true><<<gpersist, 256, 0, stream>>>(h1b, meanb, Wb2, Wb3, b2, b_skip,
                                             hpre_b, skip_b, sum2, sq2, sum3, sq3, N, NT);

  k_final<<<4096, 256, 0, stream>>>(hpre_b, skip_b, out,
                                    sum2, sq2, g2, be2, sum3, sq3, g3, be3, invN, n4);
}

// Round 10
// 292.088 us; speedup vs baseline: 2.6305x; 1.0314x over previous
//
#include <hip/hip_runtime.h>

#define D 128
#define PCHUNK 4096
#define SCAP 8192

typedef short bf16x8 __attribute__((ext_vector_type(8)));
typedef float f32x4 __attribute__((ext_vector_type(4)));

__device__ __forceinline__ ushort f2b(float f){
  unsigned u = __builtin_bit_cast(unsigned, f);
  u += 0x7fffu + ((u >> 16) & 1u);          // round-to-nearest-even
  return (ushort)(u >> 16);
}
__device__ __forceinline__ float b2f(ushort h){
  unsigned u = ((unsigned)h) << 16;
  return __builtin_bit_cast(float, u);
}

// ---------------- P0: coarse bucket histogram (bucket = dst>>8) ----------------
__global__ __launch_bounds__(256) void k_p0(const int* __restrict__ dst,
                                            int* __restrict__ bcnt, int E){
  __shared__ int h[512];
  for (int u=threadIdx.x; u<512; u+=256) h[u]=0;
  __syncthreads();
  for (long long i=(long long)blockIdx.x*256+threadIdx.x; i<E; i+=(long long)gridDim.x*256)
    atomicAdd(&h[dst[i]>>8], 1);
  __syncthreads();
  for (int u=threadIdx.x; u<512; u+=256) if (h[u]) atomicAdd(&bcnt[u], h[u]);
}

// ---------------- P1: scan buckets -> base & cursor ----------------
__global__ void k_bscan(const int* __restrict__ bcnt, int* __restrict__ bbase,
                        int* __restrict__ bcur, int nb, int E){
  __shared__ int sh[1024];
  int t = threadIdx.x;
  int v = (t<nb) ? bcnt[t] : 0;
  sh[t]=v; __syncthreads();
  for (int off=1; off<1024; off<<=1){
    int add = (t>=off)?sh[t-off]:0;
    __syncthreads();
    sh[t]+=add;
    __syncthreads();
  }
  if (t<nb){ int e=sh[t]-v; bbase[t]=e; bcur[t]=e; }
  if (t==nb) bbase[t]=E;
}

// ---------------- P2: LDS-binned partition; pairs packed as src | (dst&255)<<24 ------
__global__ __launch_bounds__(256) void k_part(const int* __restrict__ src,
        const int* __restrict__ dst, int* __restrict__ bcur,
        unsigned* __restrict__ pairs, int E){
  __shared__ int hist[512], offA[512], offB[512], gbase[512];
  __shared__ int sS[PCHUNK], sD[PCHUNK];
  const int t = threadIdx.x;
  const int base = blockIdx.x * PCHUNK;
  const int cnt = min(PCHUNK, E - base);
  for (int u=t; u<512; u+=256) hist[u]=0;
  __syncthreads();
  int rs[16], rd[16];
  #pragma unroll
  for (int j=0;j<16;j++){
    int li = j*256 + t;
    if (li < cnt){
      rs[j]=src[base+li]; rd[j]=dst[base+li];
      atomicAdd(&hist[rd[j]>>8],1);
    } else { rs[j]=0; rd[j]=-1; }
  }
  __syncthreads();
  int *cur=offA, *nxt=offB;
  for (int u=t; u<512; u+=256) cur[u]=hist[u];
  __syncthreads();
  for (int off=1; off<512; off<<=1){
    for (int u=t; u<512; u+=256) nxt[u] = cur[u] + ((u>=off)?cur[u-off]:0);
    __syncthreads();
    int* tmp=cur; cur=nxt; nxt=tmp;
  }
  for (int u=t; u<512; u+=256) nxt[u] = cur[u]-hist[u];
  __syncthreads();
  #pragma unroll
  for (int j=0;j<16;j++){
    if (j*256+t < cnt){
      int b = rd[j]>>8;
      int p = atomicAdd(&nxt[b],1);
      sS[p]=rs[j]; sD[p]=rd[j];
    }
  }
  __syncthreads();
  for (int u=t; u<512; u+=256){
    int c = hist[u];
    if (c>0) gbase[u] = atomicAdd(&bcur[u], c);
  }
  __syncthreads();
  #pragma unroll
  for (int j=0;j<16;j++){
    int idx = j*256+t;
    if (idx<cnt){
      int d = sD[idx]; int b = d>>8;
      int gpos = gbase[b] + (idx - (cur[b]-hist[b]));
      pairs[gpos] = (unsigned)sS[idx] | ((unsigned)(d & 255) << 24);
    }
  }
}

// ---------------- P3: per-bucket exact counting sort -> slots + offs ----------------
__global__ __launch_bounds__(256) void k_sortb(const unsigned* __restrict__ pairs,
        const int* __restrict__ bbase, int* __restrict__ offs,
        int* __restrict__ slots, int N, int NB){
  __shared__ int nh[256], nc[256], sc[256];
  __shared__ int stage[SCAP];
  const int b = blockIdx.x, t = threadIdx.x;
  const int base = bbase[b];
  const int cnt  = bbase[b+1] - base;
  nh[t]=0; __syncthreads();
  for (int i=t;i<cnt;i+=256) atomicAdd(&nh[pairs[base+i] >> 24],1);
  __syncthreads();
  int v = nh[t];
  sc[t]=v; __syncthreads();
  for (int off=1; off<256; off<<=1){
    int add = (t>=off)?sc[t-off]:0;
    __syncthreads();
    sc[t]+=add;
    __syncthreads();
  }
  int excl = sc[t]-v;
  nc[t]=excl;
  int node = (b<<8)+t;
  if (node<N) offs[node]=base+excl;
  if (b==NB-1 && t==0) offs[N]=bbase[NB];
  __syncthreads();
  if (cnt<=SCAP){
    for (int i=t;i<cnt;i+=256){
      unsigned p = pairs[base+i];
      int pos = atomicAdd(&nc[p >> 24],1);
      stage[pos]=(int)(p & 0xffffffu);
    }
    __syncthreads();
    for (int i=t;i<cnt;i+=256) slots[base+i]=stage[i];
  } else {
    for (int i=t;i<cnt;i+=256){
      unsigned p = pairs[base+i];
      int pos = atomicAdd(&nc[p >> 24],1);
      slots[base+pos]=(int)(p & 0xffffffu);
    }
  }
}

// ---------------- f32 -> bf16 cast ----------------
__global__ __launch_bounds__(256) void k_xcast(const float* __restrict__ x,
                                               ushort* __restrict__ xb, long long n4){
  long long i = (long long)blockIdx.x*256 + threadIdx.x;
  const long long stride = (long long)gridDim.x*256;
  for (; i < n4; i += stride){
    float4 v = reinterpret_cast<const float4*>(x)[i];
    ushort4 o;
    o.x = f2b(v.x); o.y = f2b(v.y); o.z = f2b(v.z); o.w = f2b(v.w);
    reinterpret_cast<ushort4*>(xb)[i] = o;
  }
}

// ---------------- all weight transposes in ONE launch ----------------
__global__ __launch_bounds__(256) void k_wtall(
    const float* __restrict__ w_self1, const float* __restrict__ w_neigh1,
    const float* __restrict__ w_self2, const float* __restrict__ w_neigh2,
    const float* __restrict__ w_skip,
    ushort* __restrict__ Wb1, ushort* __restrict__ Wb2, ushort* __restrict__ Wb3){
  const int grp = blockIdx.x >> 6;            // 0..4
  const int idx = (blockIdx.x & 63)*256 + threadIdx.x;  // 0..16383
  const int k = idx >> 7, c = idx & 127;
  const float* W; ushort* Wb; int K, k0;
  switch (grp){
    case 0: W=w_self1;  Wb=Wb1; K=256; k0=0;   break;
    case 1: W=w_neigh1; Wb=Wb1; K=256; k0=128; break;
    case 2: W=w_self2;  Wb=Wb2; K=256; k0=0;   break;
    case 3: W=w_neigh2; Wb=Wb2; K=256; k0=128; break;
    default:W=w_skip;   Wb=Wb3; K=128; k0=0;   break;
  }
  Wb[(size_t)c*K + k0 + k] = f2b(W[idx]);
}

// ---------------- gather-mean (bf16 in/out): 64 threads/node, pipelined 8-edge groups ----
// (R5 version — best measured: 67.7 us, 177 MB fetch; random-fill-bound floor)
__global__ __launch_bounds__(256) void k_gatherb(const ushort* __restrict__ Xb,
        const int* __restrict__ slots, const int* __restrict__ offs,
        ushort* __restrict__ meanb, int N){
  int node = blockIdx.x*4 + (threadIdx.x >> 6);
  int c2 = (threadIdx.x & 63) * 2;            // this lane's channel pair
  if (node >= N) return;
  const int beg = offs[node], end = offs[node+1];
  float sx0=0,sy0=0,sx1=0,sy1=0,sx2=0,sy2=0,sx3=0,sy3=0;
  int j = beg;
  while (j < end && (j & 3)){
    unsigned u = *reinterpret_cast<const unsigned*>(&Xb[(size_t)slots[j]*D + c2]);
    sx0 += b2f((ushort)u); sy0 += b2f((ushort)(u>>16));
    ++j;
  }
  const int nfull = (end - j) >> 2;
  const int4* sp = reinterpret_cast<const int4*>(slots + j);

#define G8(ia, ib) { \
    unsigned u0 = *reinterpret_cast<const unsigned*>(&Xb[(size_t)(ia).x*D + c2]); \
    unsigned u1 = *reinterpret_cast<const unsigned*>(&Xb[(size_t)(ia).y*D + c2]); \
    unsigned u2 = *reinterpret_cast<const unsigned*>(&Xb[(size_t)(ia).z*D + c2]); \
    unsigned u3 = *reinterpret_cast<const unsigned*>(&Xb[(size_t)(ia).w*D + c2]); \
    unsigned u4 = *reinterpret_cast<const unsigned*>(&Xb[(size_t)(ib).x*D + c2]); \
    unsigned u5 = *reinterpret_cast<const unsigned*>(&Xb[(size_t)(ib).y*D + c2]); \
    unsigned u6 = *reinterpret_cast<const unsigned*>(&Xb[(size_t)(ib).z*D + c2]); \
    unsigned u7 = *reinterpret_cast<const unsigned*>(&Xb[(size_t)(ib).w*D + c2]); \
    sx0 += b2f((ushort)u0); sy0 += b2f((ushort)(u0>>16)); \
    sx1 += b2f((ushort)u1); sy1 += b2f((ushort)(u1>>16)); \
    sx2 += b2f((ushort)u2); sy2 += b2f((ushort)(u2>>16)); \
    sx3 += b2f((ushort)u3); sy3 += b2f((ushort)(u3>>16)); \
    sx0 += b2f((ushort)u4); sy0 += b2f((ushort)(u4>>16)); \
    sx1 += b2f((ushort)u5); sy1 += b2f((ushort)(u5>>16)); \
    sx2 += b2f((ushort)u6); sy2 += b2f((ushort)(u6>>16)); \
    sx3 += b2f((ushort)u7); sy3 += b2f((ushort)(u7>>16)); }

  int g = 0;
  if (nfull >= 2){
    int4 ia = sp[0], ib = sp[1];
    for (g = 2; g + 2 <= nfull; g += 2){
      int4 na = sp[g], nb = sp[g+1];
      G8(ia, ib);
      ia = na; ib = nb;
    }
    G8(ia, ib);
  }
  if (g < nfull){
    int4 ia = sp[g];
    unsigned u0 = *reinterpret_cast<const unsigned*>(&Xb[(size_t)ia.x*D + c2]);
    unsigned u1 = *reinterpret_cast<const unsigned*>(&Xb[(size_t)ia.y*D + c2]);
    unsigned u2 = *reinterpret_cast<const unsigned*>(&Xb[(size_t)ia.z*D + c2]);
    unsigned u3 = *reinterpret_cast<const unsigned*>(&Xb[(size_t)ia.w*D + c2]);
    sx0 += b2f((ushort)u0); sy0 += b2f((ushort)(u0>>16));
    sx1 += b2f((ushort)u1); sy1 += b2f((ushort)(u1>>16));
    sx2 += b2f((ushort)u2); sy2 += b2f((ushort)(u2>>16));
    sx3 += b2f((ushort)u3); sy3 += b2f((ushort)(u3>>16));
  }
  j += 4*nfull;
  for (; j < end; ++j){
    unsigned u = *reinterpret_cast<const unsigned*>(&Xb[(size_t)slots[j]*D + c2]);
    sx0 += b2f((ushort)u); sy0 += b2f((ushort)(u>>16));
  }
#undef G8
  float deg = (float)(end - beg);
  float rc = deg > 0.f ? 1.0f/deg : 0.f;
  unsigned o = (unsigned)f2b((sx0+sx1+sx2+sx3)*rc)
             | ((unsigned)f2b((sy0+sy1+sy2+sy3)*rc) << 16);
  *reinterpret_cast<unsigned*>(&meanb[(size_t)node*D + c2]) = o;
}

// ---------------- W-resident persistent MFMA GEMM: 128x128 tile, 64x64 waves ----------
// All of W (and Wk) staged into LDS ONCE per persistent block (invariant across tiles):
// Wt8[8][128][40] = 80KB (+Wkt4 40KB if SKIP) + A dbuf 20KB + stats ~= 142KB LDS,
// 1 block/CU (occupancy was falsified as the limiter in R3). Per k-step staging is
// A-only: 2 int4 loads + 2 ds_writes per thread (was 5+5). 4-deep A register
// lookahead; raw s_barrier with lgkmcnt(0) only; setprio around MFMA cluster.
template<bool SKIP>
__global__ __launch_bounds__(256, 1) void k_mfma(
    const ushort* __restrict__ A0, const ushort* __restrict__ A1,
    const ushort* __restrict__ Wb, const ushort* __restrict__ Wk,
    const float* __restrict__ bias, const float* __restrict__ biasK,
    ushort* __restrict__ C, ushort* __restrict__ Ck,
    float* __restrict__ gS, float* __restrict__ gQ,
    float* __restrict__ gSK, float* __restrict__ gQK, int N, int NT)
{
  __shared__ ushort Wt8[8][128][40];
  __shared__ ushort Wkt4[SKIP ? 4*128*40 : 1];
  __shared__ ushort At[2][128][40];
  __shared__ float shS[128], shQ[128], shSK[SKIP?128:1], shQK[SKIP?128:1];
  const int tid = threadIdx.x;
  if (tid < 128){ shS[tid]=0.f; shQ[tid]=0.f; if (SKIP){ shSK[tid]=0.f; shQK[tid]=0.f; } }
  const int bid = blockIdx.x, gridN = gridDim.x;
  const int lane = tid & 63, wid = tid >> 6;
  const int wr = wid >> 1, wc = wid & 1;
  const int lr = lane & 15, kq = lane >> 4;
  const int sr4 = tid >> 2, s8 = (tid & 3) * 8;   // staging rows sr4 and sr4+64

  // ---- W prologue: stage all weight slices once ----
  #pragma unroll
  for (int s=0;s<8;s++){
    *reinterpret_cast<int4*>(&Wt8[s][sr4][s8]) =
        *reinterpret_cast<const int4*>(&Wb[(size_t)sr4*256 + s*32 + s8]);
    *reinterpret_cast<int4*>(&Wt8[s][sr4+64][s8]) =
        *reinterpret_cast<const int4*>(&Wb[(size_t)(sr4+64)*256 + s*32 + s8]);
  }
  if (SKIP){
    #pragma unroll
    for (int s=0;s<4;s++){
      *reinterpret_cast<int4*>(&Wkt4[((s*128) + sr4)*40 + s8]) =
          *reinterpret_cast<const int4*>(&Wk[(size_t)sr4*128 + s*32 + s8]);
      *reinterpret_cast<int4*>(&Wkt4[((s*128) + sr4 + 64)*40 + s8]) =
          *reinterpret_cast<const int4*>(&Wk[(size_t)(sr4+64)*128 + s*32 + s8]);
    }
  }

  // 4 named A load-sets, 2 int4 each (rows sr4, sr4+64)
  int4 va0a,va0b, va1a,va1b, va2a,va2b, va3a,va3b;

#define LOADA(S, GT, TT) { \
    int gr0_ = (GT)*128 + sr4;      if (gr0_ >= N) gr0_ = N-1; \
    int gr1_ = (GT)*128 + sr4 + 64; if (gr1_ >= N) gr1_ = N-1; \
    const ushort* As_ = ((TT) >= 4) ? A1 : A0; \
    const int ka_ = ((TT) & 3) * 32; \
    va##S##a = *reinterpret_cast<const int4*>(&As_[(size_t)gr0_*D + ka_ + s8]); \
    va##S##b = *reinterpret_cast<const int4*>(&As_[(size_t)gr1_*D + ka_ + s8]); }

#define WRITEA(S, BW) { \
    *reinterpret_cast<int4*>(&At[BW][sr4][s8]) = va##S##a; \
    *reinterpret_cast<int4*>(&At[BW][sr4+64][s8]) = va##S##b; }

#define PBAR() { asm volatile("s_waitcnt lgkmcnt(0)" ::: "memory"); \
    __builtin_amdgcn_s_barrier(); __builtin_amdgcn_sched_barrier(0); }

#define STEPBODY(BR, TT, WITHK, ...) { \
    bf16x8 af0 = *reinterpret_cast<const bf16x8*>(&At[BR][64*wr + lr][kq*8]); \
    bf16x8 af1 = *reinterpret_cast<const bf16x8*>(&At[BR][64*wr + 16 + lr][kq*8]); \
    bf16x8 af2 = *reinterpret_cast<const bf16x8*>(&At[BR][64*wr + 32 + lr][kq*8]); \
    bf16x8 af3 = *reinterpret_cast<const bf16x8*>(&At[BR][64*wr + 48 + lr][kq*8]); \
    bf16x8 bw0 = *reinterpret_cast<const bf16x8*>(&Wt8[TT][64*wc + lr][kq*8]); \
    bf16x8 bw1 = *reinterpret_cast<const bf16x8*>(&Wt8[TT][64*wc + 16 + lr][kq*8]); \
    bf16x8 bw2 = *reinterpret_cast<const bf16x8*>(&Wt8[TT][64*wc + 32 + lr][kq*8]); \
    bf16x8 bw3 = *reinterpret_cast<const bf16x8*>(&Wt8[TT][64*wc + 48 + lr][kq*8]); \
    bf16x8 bk0{}, bk1{}, bk2{}, bk3{}; \
    if (SKIP && (WITHK)){ \
      bk0 = *reinterpret_cast<const bf16x8*>(&Wkt4[(((TT)&3)*128 + 64*wc + lr)*40 + kq*8]); \
      bk1 = *reinterpret_cast<const bf16x8*>(&Wkt4[(((TT)&3)*128 + 64*wc + 16 + lr)*40 + kq*8]); \
      bk2 = *reinterpret_cast<const bf16x8*>(&Wkt4[(((TT)&3)*128 + 64*wc + 32 + lr)*40 + kq*8]); \
      bk3 = *reinterpret_cast<const bf16x8*>(&Wkt4[(((TT)&3)*128 + 64*wc + 48 + lr)*40 + kq*8]); \
    } \
    __VA_ARGS__; \
    __builtin_amdgcn_s_setprio(1); \
    acc[0][0] = __builtin_amdgcn_mfma_f32_16x16x32_bf16(af0, bw0, acc[0][0], 0,0,0); \
    acc[0][1] = __builtin_amdgcn_mfma_f32_16x16x32_bf16(af0, bw1, acc[0][1], 0,0,0); \
    acc[0][2] = __builtin_amdgcn_mfma_f32_16x16x32_bf16(af0, bw2, acc[0][2], 0,0,0); \
    acc[0][3] = __builtin_amdgcn_mfma_f32_16x16x32_bf16(af0, bw3, acc[0][3], 0,0,0); \
    acc[1][0] = __builtin_amdgcn_mfma_f32_16x16x32_bf16(af1, bw0, acc[1][0], 0,0,0); \
    acc[1][1] = __builtin_amdgcn_mfma_f32_16x16x32_bf16(af1, bw1, acc[1][1], 0,0,0); \
    acc[1][2] = __builtin_amdgcn_mfma_f32_16x16x32_bf16(af1, bw2, acc[1][2], 0,0,0); \
    acc[1][3] = __builtin_amdgcn_mfma_f32_16x16x32_bf16(af1, bw3, acc[1][3], 0,0,0); \
    acc[2][0] = __builtin_amdgcn_mfma_f32_16x16x32_bf16(af2, bw0, acc[2][0], 0,0,0); \
    acc[2][1] = __builtin_amdgcn_mfma_f32_16x16x32_bf16(af2, bw1, acc[2][1], 0,0,0); \
    acc[2][2] = __builtin_amdgcn_mfma_f32_16x16x32_bf16(af2, bw2, acc[2][2], 0,0,0); \
    acc[2][3] = __builtin_amdgcn_mfma_f32_16x16x32_bf16(af2, bw3, acc[2][3], 0,0,0); \
    acc[3][0] = __builtin_amdgcn_mfma_f32_16x16x32_bf16(af3, bw0, acc[3][0], 0,0,0); \
    acc[3][1] = __builtin_amdgcn_mfma_f32_16x16x32_bf16(af3, bw1, acc[3][1], 0,0,0); \
    acc[3][2] = __builtin_amdgcn_mfma_f32_16x16x32_bf16(af3, bw2, acc[3][2], 0,0,0); \
    acc[3][3] = __builtin_amdgcn_mfma_f32_16x16x32_bf16(af3, bw3, acc[3][3], 0,0,0); \
    if (SKIP && (WITHK)){ \
      accK[0][0] = __builtin_amdgcn_mfma_f32_16x16x32_bf16(af0, bk0, accK[0][0], 0,0,0); \
      accK[0][1] = __builtin_amdgcn_mfma_f32_16x16x32_bf16(af0, bk1, accK[0][1], 0,0,0); \
      accK[0][2] = __builtin_amdgcn_mfma_f32_16x16x32_bf16(af0, bk2, accK[0][2], 0,0,0); \
      accK[0][3] = __builtin_amdgcn_mfma_f32_16x16x32_bf16(af0, bk3, accK[0][3], 0,0,0); \
      accK[1][0] = __builtin_amdgcn_mfma_f32_16x16x32_bf16(af1, bk0, accK[1][0], 0,0,0); \
      accK[1][1] = __builtin_amdgcn_mfma_f32_16x16x32_bf16(af1, bk1, accK[1][1], 0,0,0); \
      accK[1][2] = __builtin_amdgcn_mfma_f32_16x16x32_bf16(af1, bk2, accK[1][2], 0,0,0); \
      accK[1][3] = __builtin_amdgcn_mfma_f32_16x16x32_bf16(af1, bk3, accK[1][3], 0,0,0); \
      accK[2][0] = __builtin_amdgcn_mfma_f32_16x16x32_bf16(af2, bk0, accK[2][0], 0,0,0); \
      accK[2][1] = __builtin_amdgcn_mfma_f32_16x16x32_bf16(af2, bk1, accK[2][1], 0,0,0); \
      accK[2][2] = __builtin_amdgcn_mfma_f32_16x16x32_bf16(af2, bk2, accK[2][2], 0,0,0); \
      accK[2][3] = __builtin_amdgcn_mfma_f32_16x16x32_bf16(af2, bk3, accK[2][3], 0,0,0); \
      accK[3][0] = __builtin_amdgcn_mfma_f32_16x16x32_bf16(af3, bk0, accK[3][0], 0,0,0); \
      accK[3][1] = __builtin_amdgcn_mfma_f32_16x16x32_bf16(af3, bk1, accK[3][1], 0,0,0); \
      accK[3][2] = __builtin_amdgcn_mfma_f32_16x16x32_bf16(af3, bk2, accK[3][2], 0,0,0); \
      accK[3][3] = __builtin_amdgcn_mfma_f32_16x16x32_bf16(af3, bk3, accK[3][3], 0,0,0); \
    } \
    __builtin_amdgcn_s_setprio(0); }

  f32x4 acc[4][4], accK[SKIP?4:1][SKIP?4:1];
  #pragma unroll
  for (int m=0;m<4;m++)
    #pragma unroll
    for (int n=0;n<4;n++){
      acc[m][n] = (f32x4){0.f,0.f,0.f,0.f};
      if (SKIP) accK[m][n] = (f32x4){0.f,0.f,0.f,0.f};
    }
  float bs[4]={0,0,0,0}, bq[4]={0,0,0,0}, bsk[4]={0,0,0,0}, bqk[4]={0,0,0,0};
  float bv[4], bkv[4];
  #pragma unroll
  for (int n=0;n<4;n++){
    bv[n] = bias[64*wc + 16*n + lr];
    bkv[n] = SKIP ? biasK[64*wc + 16*n + lr] : 0.f;
  }

  // A prologue: prime 4 sets (k-steps 0..3 of first tile), stage step 0 into buf0
  {
    const int t0 = bid;
    LOADA(0, t0, 0);
    LOADA(1, t0, 1);
    LOADA(2, t0, 2);
    LOADA(3, t0, 3);
    WRITEA(0, 0);
    PBAR();                      // also covers the W staging ds_writes above
  }

  for (int tile = bid; tile < NT; tile += gridN){
    const int tnext = tile + gridN;
    const bool hasnext = (tnext < NT);
    STEPBODY(0, 0, 1, LOADA(0, tile, 4));
    WRITEA(1, 1); PBAR();
    STEPBODY(1, 1, 1, LOADA(1, tile, 5));
    WRITEA(2, 0); PBAR();
    STEPBODY(0, 2, 1, LOADA(2, tile, 6));
    WRITEA(3, 1); PBAR();
    STEPBODY(1, 3, 1, LOADA(3, tile, 7));
    WRITEA(0, 0); PBAR();
    STEPBODY(0, 4, 0, if (hasnext) LOADA(0, tnext, 0));
    WRITEA(1, 1); PBAR();
    STEPBODY(1, 5, 0, if (hasnext) LOADA(1, tnext, 1));
    WRITEA(2, 0); PBAR();
    STEPBODY(0, 6, 0, if (hasnext) LOADA(2, tnext, 2));
    WRITEA(3, 1); PBAR();
    STEPBODY(1, 7, 0, if (hasnext) LOADA(3, tnext, 3));
    if (hasnext){ WRITEA(0, 0); PBAR(); }

    // per-tile epilogue (stores overlap next tile's in-flight loads / ds_reads)
    #pragma unroll
    for (int m=0;m<4;m++){
      #pragma unroll
      for (int r=0;r<4;r++){
        int row = tile*128 + 64*wr + 16*m + kq*4 + r;
        if (row < N){
          #pragma unroll
          for (int n=0;n<4;n++){
            int col = 64*wc + 16*n + lr;
            float v = acc[m][n][r] + bv[n];
            C[(size_t)row*D + col] = f2b(v);
            bs[n] += v; bq[n] += v*v;
            if (SKIP){
              float u = accK[m][n][r] + bkv[n];
              Ck[(size_t)row*D + col] = f2b(u);
              bsk[n] += u; bqk[n] += u*u;
            }
          }
        }
      }
    }
    #pragma unroll
    for (int m=0;m<4;m++)
      #pragma unroll
      for (int n=0;n<4;n++){
        acc[m][n] = (f32x4){0.f,0.f,0.f,0.f};
        if (SKIP) accK[m][n] = (f32x4){0.f,0.f,0.f,0.f};
      }
  }
#undef LOADA
#undef WRITEA
#undef PBAR
#undef STEPBODY

  // one stat-reduction per block
  #pragma unroll
  for (int n=0;n<4;n++){
    float s = bs[n], q = bq[n];
    s += __shfl_xor(s,16); s += __shfl_xor(s,32);
    q += __shfl_xor(q,16); q += __shfl_xor(q,32);
    if (kq == 0){
      int col = 64*wc + 16*n + lr;
      atomicAdd(&shS[col], s);
      atomicAdd(&shQ[col], q);
    }
    if (SKIP){
      float sk = bsk[n], qk = bqk[n];
      sk += __shfl_xor(sk,16); sk += __shfl_xor(sk,32);
      qk += __shfl_xor(qk,16); qk += __shfl_xor(qk,32);
      if (kq == 0){
        int col = 64*wc + 16*n + lr;
        atomicAdd(&shSK[col], sk);
        atomicAdd(&shQK[col], qk);
      }
    }
  }
  __syncthreads();
  if (tid < 128){
    unsafeAtomicAdd(&gS[tid], shS[tid]);
    unsafeAtomicAdd(&gQ[tid], shQ[tid]);
    if (SKIP){
      unsafeAtomicAdd(&gSK[tid], shSK[tid]);
      unsafeAtomicAdd(&gQK[tid], shQK[tid]);
    }
  }
}

// ---------------- BN + ReLU, bf16 in -> bf16 out (BN affine computed in-block) --------
__global__ __launch_bounds__(256) void k_bnrelub(const ushort* __restrict__ hpre,
      ushort* __restrict__ hb,
      const float* __restrict__ sum, const float* __restrict__ sq,
      const float* __restrict__ g, const float* __restrict__ be,
      float invN, long long n4){
  __shared__ float A[128], B[128];
  if (threadIdx.x < 128){
    int c = threadIdx.x;
    float m = sum[c]*invN;
    float v = sq[c]*invN - m*m;
    float a = g[c]*rsqrtf(fmaxf(v, 0.f) + 1e-5f);
    A[c] = a;
    B[c] = be[c] - m*a;
  }
  __syncthreads();
  long long i = (long long)blockIdx.x*256 + threadIdx.x;
  const long long stride = (long long)gridDim.x*256;
  for (; i < n4; i += stride){
    int c = ((int)(i & 31)) << 2;
    float4 a = *reinterpret_cast<const float4*>(A + c);
    float4 b = *reinterpret_cast<const float4*>(B + c);
    ushort4 hv = reinterpret_cast<const ushort4*>(hpre)[i];
    ushort4 o;
    o.x = f2b(fmaxf(a.x*b2f(hv.x) + b.x, 0.f));
    o.y = f2b(fmaxf(a.y*b2f(hv.y) + b.y, 0.f));
    o.z = f2b(fmaxf(a.z*b2f(hv.z) + b.z, 0.f));
    o.w = f2b(fmaxf(a.w*b2f(hv.w) + b.w, 0.f));
    reinterpret_cast<ushort4*>(hb)[i] = o;
  }
}

// ---------------- final: out = relu(bn2(h2) + bn3(skip)), f32 out (BN in-block) -------
__global__ __launch_bounds__(256) void k_final(const ushort* __restrict__ h2,
      const ushort* __restrict__ sk, float* __restrict__ out,
      const float* __restrict__ sum2, const float* __restrict__ sq2,
      const float* __restrict__ g2, const float* __restrict__ be2,
      const float* __restrict__ sum3, const float* __restrict__ sq3,
      const float* __restrict__ g3, const float* __restrict__ be3,
      float invN, long long n4){
  __shared__ float A2[128], B2[128], A3[128], B3[128];
  if (threadIdx.x < 128){
    int c = threadIdx.x;
    float m2 = sum2[c]*invN;
    float v2 = sq2[c]*invN - m2*m2;
    float a2 = g2[c]*rsqrtf(fmaxf(v2, 0.f) + 1e-5f);
    A2[c] = a2; B2[c] = be2[c] - m2*a2;
    float m3 = sum3[c]*invN;
    float v3 = sq3[c]*invN - m3*m3;
    float a3 = g3[c]*rsqrtf(fmaxf(v3, 0.f) + 1e-5f);
    A3[c] = a3; B3[c] = be3[c] - m3*a3;
  }
  __syncthreads();
  long long i = (long long)blockIdx.x*256 + threadIdx.x;
  const long long stride = (long long)gridDim.x*256;
  for (; i < n4; i += stride){
    int c = ((int)(i & 31)) << 2;
    float4 a2 = *reinterpret_cast<const float4*>(A2 + c);
    float4 b2 = *reinterpret_cast<const float4*>(B2 + c);
    float4 a3 = *reinterpret_cast<const float4*>(A3 + c);
    float4 b3 = *reinterpret_cast<const float4*>(B3 + c);
    ushort4 h = reinterpret_cast<const ushort4*>(h2)[i];
    ushort4 s = reinterpret_cast<const ushort4*>(sk)[i];
    float4 v;
    v.x = fmaxf(a2.x*b2f(h.x) + b2.x + a3.x*b2f(s.x) + b3.x, 0.f);
    v.y = fmaxf(a2.y*b2f(h.y) + b2.y + a3.y*b2f(s.y) + b3.y, 0.f);
    v.z = fmaxf(a2.z*b2f(h.z) + b2.z + a3.z*b2f(s.z) + b3.z, 0.f);
    v.w = fmaxf(a2.w*b2f(h.w) + b2.w + a3.w*b2f(s.w) + b3.w, 0.f);
    reinterpret_cast<float4*>(out)[i] = v;
  }
}

extern "C" void kernel_launch(void* const* d_in, const int* in_sizes, int n_in,
                              void* d_out, int out_size, void* d_ws, size_t ws_size,
                              hipStream_t stream) {
  const float* x        = (const float*)d_in[0];
  const int*   src      = (const int*)  d_in[1];
  const int*   dst      = (const int*)  d_in[2];
  const float* w_self1  = (const float*)d_in[3];
  const float* w_neigh1 = (const float*)d_in[4];
  const float* b1       = (const float*)d_in[5];
  const float* w_self2  = (const float*)d_in[6];
  const float* w_neigh2 = (const float*)d_in[7];
  const float* b2       = (const float*)d_in[8];
  const float* w_skip   = (const float*)d_in[9];
  const float* b_skip   = (const float*)d_in[10];
  const float* g1       = (const float*)d_in[11];
  const float* be1      = (const float*)d_in[12];
  const float* g2       = (const float*)d_in[13];
  const float* be2      = (const float*)d_in[14];
  const float* g3       = (const float*)d_in[15];
  const float* be3      = (const float*)d_in[16];
  (void)n_in; (void)ws_size;

  const int N = in_sizes[0] / D;
  const int E = in_sizes[1];
  const int NB = (N + 255) >> 8;
  float* out = (float*)d_out;

  // ---- workspace layout ----
  char* p = (char*)d_ws;
  const size_t nd2 = (((size_t)N * D * 2) + 255) / 256 * 256;   // bf16 [N][D]
  ushort* meanb  = (ushort*)p; p += nd2;
  ushort* h1b    = (ushort*)p; p += nd2;
  ushort* hpre_b = (ushort*)p; p += nd2;     // h1pre, then h2pre (aliased)
  ushort* skip_b = (ushort*)p; p += nd2;
  ushort* Wb1    = (ushort*)p; p += 256*128*2;
  ushort* Wb2    = (ushort*)p; p += 256*128*2;
  ushort* Wb3    = (ushort*)p; p += 128*128*2;
  int*    offs   = (int*)p;   p += (((size_t)(N+1)*4) + 255) / 256 * 256;
  int*    bcnt   = (int*)p;   p += 2304;
  float*  st     = (float*)p; p += 1536*sizeof(float);
  int*    bbase  = (int*)p;   p += 2304;
  int*    bcur   = (int*)p;   p += 2048;
  float *sum1=st,      *sq1=st+128,  *sum2=st+256, *sq2=st+384, *sum3=st+512, *sq3=st+640;

  // scratch in d_out (dead before k_final rewrites all of d_out)
  const size_t slpad = (((size_t)E*4) + 255) / 256 * 256;
  const size_t xbpad = (((size_t)N*D*2) + 255) / 256 * 256;
  int*      slots = (int*)d_out;
  ushort*   xb    = (ushort*)((char*)d_out + slpad);
  unsigned* pairs = (unsigned*)((char*)d_out + slpad + xbpad);

  hipMemsetAsync(bcnt, 0, 2304 + 1536*sizeof(float), stream);

  const long long n4 = (long long)N * D / 4;

  // --- casts / weight prep (one launch for all 5 transposes) ---
  k_xcast<<<2048, 256, 0, stream>>>(x, xb, n4);
  k_wtall<<<320, 256, 0, stream>>>(w_self1, w_neigh1, w_self2, w_neigh2, w_skip,
                                   Wb1, Wb2, Wb3);

  // --- CSR build via 2-level counting sort ---
  k_p0<<<1024, 256, 0, stream>>>(dst, bcnt, E);
  k_bscan<<<1, 1024, 0, stream>>>(bcnt, bbase, bcur, NB, E);
  k_part<<<(E + PCHUNK - 1)/PCHUNK, 256, 0, stream>>>(src, dst, bcur, pairs, E);
  k_sortb<<<NB, 256, 0, stream>>>(pairs, bbase, offs, slots, N, NB);

  const int gablocks = (N + 3) / 4;
  const int NT = (N + 127) / 128;
  const int gpersist = 256;                 // 1 persistent block per CU (142KB LDS)
  const float invN = 1.0f / (float)N;

  // --- layer 1 ---
  k_gatherb<<<gablocks, 256, 0, stream>>>(xb, slots, offs, meanb, N);
  k_mfma<false><<<gpersist, 256, 0, stream>>>(xb, meanb, Wb1, nullptr, b1, nullptr,
                                              hpre_b, nullptr, sum1, sq1, nullptr, nullptr, N, NT);
  k_bnrelub<<<4096, 256, 0, stream>>>(hpre_b, h1b, sum1, sq1, g1, be1, invN, n4);

  // --- layer 2 aggregation ---
  k_gatherb<<<gablocks, 256, 0, stream>>>(h1b, slots, offs, meanb, N);

  // fused layer-2 + skip GEMM (shares A fragments; h1b read once)
  k_mfma<true><<<gpersist, 256, 0, stream>>>(h1b, meanb, Wb2, Wb3, b2, b_skip,
                                             hpre_b, skip_b, sum2, sq2, sum3, sq3, N, NT);

  k_final<<<4096, 256, 0, stream>>>(hpre_b, skip_b, out,
                                    sum2, sq2, g2, be2, sum3, sq3, g3, be3, invN, n4);
}

// Round 11
// 285.578 us; speedup vs baseline: 2.6905x; 1.0228x over previous
//
#include <hip/hip_runtime.h>

#define D 128
#define PCHUNK 4096
#define SCAP 8192

typedef short bf16x8 __attribute__((ext_vector_type(8)));
typedef float f32x4 __attribute__((ext_vector_type(4)));

__device__ __forceinline__ ushort f2b(float f){
  unsigned u = __builtin_bit_cast(unsigned, f);
  u += 0x7fffu + ((u >> 16) & 1u);          // round-to-nearest-even
  return (ushort)(u >> 16);
}
__device__ __forceinline__ float b2f(ushort h){
  unsigned u = ((unsigned)h) << 16;
  return __builtin_bit_cast(float, u);
}

// unpack 8 bf16, apply per-channel affine+relu, repack (channels cb..cb+7)
__device__ __forceinline__ int4 bnpack8(int4 v, float4 a0, float4 a1, float4 b0, float4 b1){
  unsigned w0=(unsigned)v.x, w1=(unsigned)v.y, w2=(unsigned)v.z, w3=(unsigned)v.w;
  float x0 = fmaxf(fmaf(a0.x, b2f((ushort)w0),        b0.x), 0.f);
  float x1 = fmaxf(fmaf(a0.y, b2f((ushort)(w0>>16)),  b0.y), 0.f);
  float x2 = fmaxf(fmaf(a0.z, b2f((ushort)w1),        b0.z), 0.f);
  float x3 = fmaxf(fmaf(a0.w, b2f((ushort)(w1>>16)),  b0.w), 0.f);
  float x4 = fmaxf(fmaf(a1.x, b2f((ushort)w2),        b1.x), 0.f);
  float x5 = fmaxf(fmaf(a1.y, b2f((ushort)(w2>>16)),  b1.y), 0.f);
  float x6 = fmaxf(fmaf(a1.z, b2f((ushort)w3),        b1.z), 0.f);
  float x7 = fmaxf(fmaf(a1.w, b2f((ushort)(w3>>16)),  b1.w), 0.f);
  int4 r;
  r.x = (int)((unsigned)f2b(x0) | ((unsigned)f2b(x1)<<16));
  r.y = (int)((unsigned)f2b(x2) | ((unsigned)f2b(x3)<<16));
  r.z = (int)((unsigned)f2b(x4) | ((unsigned)f2b(x5)<<16));
  r.w = (int)((unsigned)f2b(x6) | ((unsigned)f2b(x7)<<16));
  return r;
}

// ---------------- prep: weight transposes + dst histogram + x cast, ONE launch --------
// blocks [0,320): wt jobs; [320,1344): p0 histogram; [1344,3392): xcast grid-stride.
__global__ __launch_bounds__(256) void k_prep(
    const float* __restrict__ w_self1, const float* __restrict__ w_neigh1,
    const float* __restrict__ w_self2, const float* __restrict__ w_neigh2,
    const float* __restrict__ w_skip,
    ushort* __restrict__ Wb1, ushort* __restrict__ Wb2, ushort* __restrict__ Wb3,
    const int* __restrict__ dst, int* __restrict__ bcnt, int E,
    const float* __restrict__ x, ushort* __restrict__ xb, long long n4){
  __shared__ int h[512];
  const int bid = blockIdx.x;
  if (bid < 320){
    const int grp = bid >> 6;
    const int idx = (bid & 63)*256 + threadIdx.x;
    const int k = idx >> 7, c = idx & 127;
    const float* W; ushort* Wb; int K, k0;
    switch (grp){
      case 0: W=w_self1;  Wb=Wb1; K=256; k0=0;   break;
      case 1: W=w_neigh1; Wb=Wb1; K=256; k0=128; break;
      case 2: W=w_self2;  Wb=Wb2; K=256; k0=0;   break;
      case 3: W=w_neigh2; Wb=Wb2; K=256; k0=128; break;
      default:W=w_skip;   Wb=Wb3; K=128; k0=0;   break;
    }
    Wb[(size_t)c*K + k0 + k] = f2b(W[idx]);
  } else if (bid < 1344){
    const int pb = bid - 320;             // 0..1023
    for (int u=threadIdx.x; u<512; u+=256) h[u]=0;
    __syncthreads();
    for (long long i=(long long)pb*256+threadIdx.x; i<E; i+=(long long)1024*256)
      atomicAdd(&h[dst[i]>>8], 1);
    __syncthreads();
    for (int u=threadIdx.x; u<512; u+=256) if (h[u]) atomicAdd(&bcnt[u], h[u]);
  } else {
    long long i = (long long)(bid-1344)*256 + threadIdx.x;
    const long long stride = 2048LL*256;
    for (; i < n4; i += stride){
      float4 v = reinterpret_cast<const float4*>(x)[i];
      ushort4 o;
      o.x = f2b(v.x); o.y = f2b(v.y); o.z = f2b(v.z); o.w = f2b(v.w);
      reinterpret_cast<ushort4*>(xb)[i] = o;
    }
  }
}

// ---------------- P1: scan buckets -> base & cursor ----------------
__global__ void k_bscan(const int* __restrict__ bcnt, int* __restrict__ bbase,
                        int* __restrict__ bcur, int nb, int E){
  __shared__ int sh[1024];
  int t = threadIdx.x;
  int v = (t<nb) ? bcnt[t] : 0;
  sh[t]=v; __syncthreads();
  for (int off=1; off<1024; off<<=1){
    int add = (t>=off)?sh[t-off]:0;
    __syncthreads();
    sh[t]+=add;
    __syncthreads();
  }
  if (t<nb){ int e=sh[t]-v; bbase[t]=e; bcur[t]=e; }
  if (t==nb) bbase[t]=E;
}

// ---------------- P2: LDS-binned partition; pairs packed as src | (dst&255)<<24 ------
__global__ __launch_bounds__(256) void k_part(const int* __restrict__ src,
        const int* __restrict__ dst, int* __restrict__ bcur,
        unsigned* __restrict__ pairs, int E){
  __shared__ int hist[512], offA[512], offB[512], gbase[512];
  __shared__ int sS[PCHUNK], sD[PCHUNK];
  const int t = threadIdx.x;
  const int base = blockIdx.x * PCHUNK;
  const int cnt = min(PCHUNK, E - base);
  for (int u=t; u<512; u+=256) hist[u]=0;
  __syncthreads();
  int rs[16], rd[16];
  #pragma unroll
  for (int j=0;j<16;j++){
    int li = j*256 + t;
    if (li < cnt){
      rs[j]=src[base+li]; rd[j]=dst[base+li];
      atomicAdd(&hist[rd[j]>>8],1);
    } else { rs[j]=0; rd[j]=-1; }
  }
  __syncthreads();
  int *cur=offA, *nxt=offB;
  for (int u=t; u<512; u+=256) cur[u]=hist[u];
  __syncthreads();
  for (int off=1; off<512; off<<=1){
    for (int u=t; u<512; u+=256) nxt[u] = cur[u] + ((u>=off)?cur[u-off]:0);
    __syncthreads();
    int* tmp=cur; cur=nxt; nxt=tmp;
  }
  for (int u=t; u<512; u+=256) nxt[u] = cur[u]-hist[u];
  __syncthreads();
  #pragma unroll
  for (int j=0;j<16;j++){
    if (j*256+t < cnt){
      int b = rd[j]>>8;
      int p = atomicAdd(&nxt[b],1);
      sS[p]=rs[j]; sD[p]=rd[j];
    }
  }
  __syncthreads();
  for (int u=t; u<512; u+=256){
    int c = hist[u];
    if (c>0) gbase[u] = atomicAdd(&bcur[u], c);
  }
  __syncthreads();
  #pragma unroll
  for (int j=0;j<16;j++){
    int idx = j*256+t;
    if (idx<cnt){
      int d = sD[idx]; int b = d>>8;
      int gpos = gbase[b] + (idx - (cur[b]-hist[b]));
      pairs[gpos] = (unsigned)sS[idx] | ((unsigned)(d & 255) << 24);
    }
  }
}

// ---------------- P3: per-bucket exact counting sort -> slots + offs ----------------
__global__ __launch_bounds__(256) void k_sortb(const unsigned* __restrict__ pairs,
        const int* __restrict__ bbase, int* __restrict__ offs,
        int* __restrict__ slots, int N, int NB){
  __shared__ int nh[256], nc[256], sc[256];
  __shared__ int stage[SCAP];
  const int b = blockIdx.x, t = threadIdx.x;
  const int base = bbase[b];
  const int cnt  = bbase[b+1] - base;
  nh[t]=0; __syncthreads();
  for (int i=t;i<cnt;i+=256) atomicAdd(&nh[pairs[base+i] >> 24],1);
  __syncthreads();
  int v = nh[t];
  sc[t]=v; __syncthreads();
  for (int off=1; off<256; off<<=1){
    int add = (t>=off)?sc[t-off]:0;
    __syncthreads();
    sc[t]+=add;
    __syncthreads();
  }
  int excl = sc[t]-v;
  nc[t]=excl;
  int node = (b<<8)+t;
  if (node<N) offs[node]=base+excl;
  if (b==NB-1 && t==0) offs[N]=bbase[NB];
  __syncthreads();
  if (cnt<=SCAP){
    for (int i=t;i<cnt;i+=256){
      unsigned p = pairs[base+i];
      int pos = atomicAdd(&nc[p >> 24],1);
      stage[pos]=(int)(p & 0xffffffu);
    }
    __syncthreads();
    for (int i=t;i<cnt;i+=256) slots[base+i]=stage[i];
  } else {
    for (int i=t;i<cnt;i+=256){
      unsigned p = pairs[base+i];
      int pos = atomicAdd(&nc[p >> 24],1);
      slots[base+pos]=(int)(p & 0xffffffu);
    }
  }
}

// ---------------- gather-mean, optional inline BN+ReLU of the gathered rows -----------
// BN=false: mean of raw bf16 rows (layer 1). BN=true: mean of relu(a*x+b) where (a,b)
// are the layer-1 BN affine per channel (computed per-lane from sum/sq) -> eliminates
// the separate BN+ReLU pass; reads h1pre directly.
template<bool BN>
__global__ __launch_bounds__(256) void k_gatherb(const ushort* __restrict__ Xb,
        const int* __restrict__ slots, const int* __restrict__ offs,
        ushort* __restrict__ meanb, int N,
        const float* __restrict__ sum, const float* __restrict__ sq,
        const float* __restrict__ g, const float* __restrict__ be, float invN){
  int node = blockIdx.x*4 + (threadIdx.x >> 6);
  int c2 = (threadIdx.x & 63) * 2;            // this lane's channel pair
  if (node >= N) return;
  float a0=0.f,a1=0.f,b0c=0.f,b1c=0.f;
  if (BN){
    float m0 = sum[c2]*invN,   m1 = sum[c2+1]*invN;
    float v0 = sq[c2]*invN - m0*m0, v1 = sq[c2+1]*invN - m1*m1;
    a0 = g[c2]  *rsqrtf(fmaxf(v0,0.f)+1e-5f);
    a1 = g[c2+1]*rsqrtf(fmaxf(v1,0.f)+1e-5f);
    b0c = be[c2]   - m0*a0;
    b1c = be[c2+1] - m1*a1;
  }
#define AX0(x) (BN ? fmaxf(fmaf(a0,(x),b0c),0.f) : (x))
#define AX1(x) (BN ? fmaxf(fmaf(a1,(x),b1c),0.f) : (x))
  const int beg = offs[node], end = offs[node+1];
  float sx0=0,sy0=0,sx1=0,sy1=0,sx2=0,sy2=0,sx3=0,sy3=0;
  int j = beg;
  while (j < end && (j & 3)){
    unsigned u = *reinterpret_cast<const unsigned*>(&Xb[(size_t)slots[j]*D + c2]);
    sx0 += AX0(b2f((ushort)u)); sy0 += AX1(b2f((ushort)(u>>16)));
    ++j;
  }
  const int nfull = (end - j) >> 2;
  const int4* sp = reinterpret_cast<const int4*>(slots + j);

#define G8(ia, ib) { \
    unsigned u0 = *reinterpret_cast<const unsigned*>(&Xb[(size_t)(ia).x*D + c2]); \
    unsigned u1 = *reinterpret_cast<const unsigned*>(&Xb[(size_t)(ia).y*D + c2]); \
    unsigned u2 = *reinterpret_cast<const unsigned*>(&Xb[(size_t)(ia).z*D + c2]); \
    unsigned u3 = *reinterpret_cast<const unsigned*>(&Xb[(size_t)(ia).w*D + c2]); \
    unsigned u4 = *reinterpret_cast<const unsigned*>(&Xb[(size_t)(ib).x*D + c2]); \
    unsigned u5 = *reinterpret_cast<const unsigned*>(&Xb[(size_t)(ib).y*D + c2]); \
    unsigned u6 = *reinterpret_cast<const unsigned*>(&Xb[(size_t)(ib).z*D + c2]); \
    unsigned u7 = *reinterpret_cast<const unsigned*>(&Xb[(size_t)(ib).w*D + c2]); \
    sx0 += AX0(b2f((ushort)u0)); sy0 += AX1(b2f((ushort)(u0>>16))); \
    sx1 += AX0(b2f((ushort)u1)); sy1 += AX1(b2f((ushort)(u1>>16))); \
    sx2 += AX0(b2f((ushort)u2)); sy2 += AX1(b2f((ushort)(u2>>16))); \
    sx3 += AX0(b2f((ushort)u3)); sy3 += AX1(b2f((ushort)(u3>>16))); \
    sx0 += AX0(b2f((ushort)u4)); sy0 += AX1(b2f((ushort)(u4>>16))); \
    sx1 += AX0(b2f((ushort)u5)); sy1 += AX1(b2f((ushort)(u5>>16))); \
    sx2 += AX0(b2f((ushort)u6)); sy2 += AX1(b2f((ushort)(u6>>16))); \
    sx3 += AX0(b2f((ushort)u7)); sy3 += AX1(b2f((ushort)(u7>>16))); }

  int g8 = 0;
  if (nfull >= 2){
    int4 ia = sp[0], ib = sp[1];
    for (g8 = 2; g8 + 2 <= nfull; g8 += 2){
      int4 na = sp[g8], nb = sp[g8+1];
      G8(ia, ib);
      ia = na; ib = nb;
    }
    G8(ia, ib);
  }
  if (g8 < nfull){
    int4 ia = sp[g8];
    unsigned u0 = *reinterpret_cast<const unsigned*>(&Xb[(size_t)ia.x*D + c2]);
    unsigned u1 = *reinterpret_cast<const unsigned*>(&Xb[(size_t)ia.y*D + c2]);
    unsigned u2 = *reinterpret_cast<const unsigned*>(&Xb[(size_t)ia.z*D + c2]);
    unsigned u3 = *reinterpret_cast<const unsigned*>(&Xb[(size_t)ia.w*D + c2]);
    sx0 += AX0(b2f((ushort)u0)); sy0 += AX1(b2f((ushort)(u0>>16)));
    sx1 += AX0(b2f((ushort)u1)); sy1 += AX1(b2f((ushort)(u1>>16)));
    sx2 += AX0(b2f((ushort)u2)); sy2 += AX1(b2f((ushort)(u2>>16)));
    sx3 += AX0(b2f((ushort)u3)); sy3 += AX1(b2f((ushort)(u3>>16)));
  }
  j += 4*nfull;
  for (; j < end; ++j){
    unsigned u = *reinterpret_cast<const unsigned*>(&Xb[(size_t)slots[j]*D + c2]);
    sx0 += AX0(b2f((ushort)u)); sy0 += AX1(b2f((ushort)(u>>16)));
  }
#undef G8
#undef AX0
#undef AX1
  float deg = (float)(end - beg);
  float rc = deg > 0.f ? 1.0f/deg : 0.f;
  unsigned o = (unsigned)f2b((sx0+sx1+sx2+sx3)*rc)
             | ((unsigned)f2b((sy0+sy1+sy2+sy3)*rc) << 16);
  *reinterpret_cast<unsigned*>(&meanb[(size_t)node*D + c2]) = o;
}

// ---------------- W-resident persistent MFMA GEMM: 128x128 tile, 64x64 waves ----------
// All of W (and Wk) staged into LDS once per persistent block. Per k-step staging is
// A-only; 4-deep A register lookahead; raw s_barrier (lgkmcnt only); setprio on MFMA.
// SKIP=true (layer 2) additionally applies the layer-1 BN+ReLU affine to the SELF half
// (k-steps 0..3) during A-staging — A0 = h1pre, coefficients from sumA/sqA via LDS table.
template<bool SKIP>
__global__ __launch_bounds__(256, 1) void k_mfma(
    const ushort* __restrict__ A0, const ushort* __restrict__ A1,
    const ushort* __restrict__ Wb, const ushort* __restrict__ Wk,
    const float* __restrict__ bias, const float* __restrict__ biasK,
    ushort* __restrict__ C, ushort* __restrict__ Ck,
    float* __restrict__ gS, float* __restrict__ gQ,
    float* __restrict__ gSK, float* __restrict__ gQK, int N, int NT,
    const float* __restrict__ sumA, const float* __restrict__ sqA,
    const float* __restrict__ gA, const float* __restrict__ beA, float invN)
{
  __shared__ ushort Wt8[8][128][40];
  __shared__ ushort Wkt4[SKIP ? 4*128*40 : 1];
  __shared__ ushort At[2][128][40];
  __shared__ float shS[128], shQ[128], shSK[SKIP?128:1], shQK[SKIP?128:1];
  __shared__ float Af[SKIP?128:1], Bf[SKIP?128:1];
  const int tid = threadIdx.x;
  if (tid < 128){ shS[tid]=0.f; shQ[tid]=0.f; if (SKIP){ shSK[tid]=0.f; shQK[tid]=0.f; } }
  const int bid = blockIdx.x, gridN = gridDim.x;
  const int lane = tid & 63, wid = tid >> 6;
  const int wr = wid >> 1, wc = wid & 1;
  const int lr = lane & 15, kq = lane >> 4;
  const int sr4 = tid >> 2, s8 = (tid & 3) * 8;   // staging rows sr4 and sr4+64

  if (SKIP && tid < 128){
    float m = sumA[tid]*invN;
    float v = sqA[tid]*invN - m*m;
    float a = gA[tid]*rsqrtf(fmaxf(v,0.f)+1e-5f);
    Af[tid] = a;
    Bf[tid] = beA[tid] - m*a;
  }

  // ---- W prologue: stage all weight slices once ----
  #pragma unroll
  for (int s=0;s<8;s++){
    *reinterpret_cast<int4*>(&Wt8[s][sr4][s8]) =
        *reinterpret_cast<const int4*>(&Wb[(size_t)sr4*256 + s*32 + s8]);
    *reinterpret_cast<int4*>(&Wt8[s][sr4+64][s8]) =
        *reinterpret_cast<const int4*>(&Wb[(size_t)(sr4+64)*256 + s*32 + s8]);
  }
  if (SKIP){
    #pragma unroll
    for (int s=0;s<4;s++){
      *reinterpret_cast<int4*>(&Wkt4[((s*128) + sr4)*40 + s8]) =
          *reinterpret_cast<const int4*>(&Wk[(size_t)sr4*128 + s*32 + s8]);
      *reinterpret_cast<int4*>(&Wkt4[((s*128) + sr4 + 64)*40 + s8]) =
          *reinterpret_cast<const int4*>(&Wk[(size_t)(sr4+64)*128 + s*32 + s8]);
    }
  }

  // 4 named A load-sets, 2 int4 each (rows sr4, sr4+64)
  int4 va0a,va0b, va1a,va1b, va2a,va2b, va3a,va3b;

#define LOADA(S, GT, TT) { \
    int gr0_ = (GT)*128 + sr4;      if (gr0_ >= N) gr0_ = N-1; \
    int gr1_ = (GT)*128 + sr4 + 64; if (gr1_ >= N) gr1_ = N-1; \
    const ushort* As_ = ((TT) >= 4) ? A1 : A0; \
    const int ka_ = ((TT) & 3) * 32; \
    va##S##a = *reinterpret_cast<const int4*>(&As_[(size_t)gr0_*D + ka_ + s8]); \
    va##S##b = *reinterpret_cast<const int4*>(&As_[(size_t)gr1_*D + ka_ + s8]); }

#define WRITEA(S, BW, TT) { \
    int4 wa_ = va##S##a, wb_ = va##S##b; \
    if (SKIP && (TT) < 4){ \
      const int cb_ = ((TT)&3)*32 + s8; \
      float4 fa0_ = *reinterpret_cast<const float4*>(&Af[cb_]); \
      float4 fa1_ = *reinterpret_cast<const float4*>(&Af[cb_+4]); \
      float4 fb0_ = *reinterpret_cast<const float4*>(&Bf[cb_]); \
      float4 fb1_ = *reinterpret_cast<const float4*>(&Bf[cb_+4]); \
      wa_ = bnpack8(wa_, fa0_, fa1_, fb0_, fb1_); \
      wb_ = bnpack8(wb_, fa0_, fa1_, fb0_, fb1_); \
    } \
    *reinterpret_cast<int4*>(&At[BW][sr4][s8]) = wa_; \
    *reinterpret_cast<int4*>(&At[BW][sr4+64][s8]) = wb_; }

#define PBAR() { asm volatile("s_waitcnt lgkmcnt(0)" ::: "memory"); \
    __builtin_amdgcn_s_barrier(); __builtin_amdgcn_sched_barrier(0); }

#define STEPBODY(BR, TT, WITHK, ...) { \
    bf16x8 af0 = *reinterpret_cast<const bf16x8*>(&At[BR][64*wr + lr][kq*8]); \
    bf16x8 af1 = *reinterpret_cast<const bf16x8*>(&At[BR][64*wr + 16 + lr][kq*8]); \
    bf16x8 af2 = *reinterpret_cast<const bf16x8*>(&At[BR][64*wr + 32 + lr][kq*8]); \
    bf16x8 af3 = *reinterpret_cast<const bf16x8*>(&At[BR][64*wr + 48 + lr][kq*8]); \
    bf16x8 bw0 = *reinterpret_cast<const bf16x8*>(&Wt8[TT][64*wc + lr][kq*8]); \
    bf16x8 bw1 = *reinterpret_cast<const bf16x8*>(&Wt8[TT][64*wc + 16 + lr][kq*8]); \
    bf16x8 bw2 = *reinterpret_cast<const bf16x8*>(&Wt8[TT][64*wc + 32 + lr][kq*8]); \
    bf16x8 bw3 = *reinterpret_cast<const bf16x8*>(&Wt8[TT][64*wc + 48 + lr][kq*8]); \
    bf16x8 bk0{}, bk1{}, bk2{}, bk3{}; \
    if (SKIP && (WITHK)){ \
      bk0 = *reinterpret_cast<const bf16x8*>(&Wkt4[(((TT)&3)*128 + 64*wc + lr)*40 + kq*8]); \
      bk1 = *reinterpret_cast<const bf16x8*>(&Wkt4[(((TT)&3)*128 + 64*wc + 16 + lr)*40 + kq*8]); \
      bk2 = *reinterpret_cast<const bf16x8*>(&Wkt4[(((TT)&3)*128 + 64*wc + 32 + lr)*40 + kq*8]); \
      bk3 = *reinterpret_cast<const bf16x8*>(&Wkt4[(((TT)&3)*128 + 64*wc + 48 + lr)*40 + kq*8]); \
    } \
    __VA_ARGS__; \
    __builtin_amdgcn_s_setprio(1); \
    acc[0][0] = __builtin_amdgcn_mfma_f32_16x16x32_bf16(af0, bw0, acc[0][0], 0,0,0); \
    acc[0][1] = __builtin_amdgcn_mfma_f32_16x16x32_bf16(af0, bw1, acc[0][1], 0,0,0); \
    acc[0][2] = __builtin_amdgcn_mfma_f32_16x16x32_bf16(af0, bw2, acc[0][2], 0,0,0); \
    acc[0][3] = __builtin_amdgcn_mfma_f32_16x16x32_bf16(af0, bw3, acc[0][3], 0,0,0); \
    acc[1][0] = __builtin_amdgcn_mfma_f32_16x16x32_bf16(af1, bw0, acc[1][0], 0,0,0); \
    acc[1][1] = __builtin_amdgcn_mfma_f32_16x16x32_bf16(af1, bw1, acc[1][1], 0,0,0); \
    acc[1][2] = __builtin_amdgcn_mfma_f32_16x16x32_bf16(af1, bw2, acc[1][2], 0,0,0); \
    acc[1][3] = __builtin_amdgcn_mfma_f32_16x16x32_bf16(af1, bw3, acc[1][3], 0,0,0); \
    acc[2][0] = __builtin_amdgcn_mfma_f32_16x16x32_bf16(af2, bw0, acc[2][0], 0,0,0); \
    acc[2][1] = __builtin_amdgcn_mfma_f32_16x16x32_bf16(af2, bw1, acc[2][1], 0,0,0); \
    acc[2][2] = __builtin_amdgcn_mfma_f32_16x16x32_bf16(af2, bw2, acc[2][2], 0,0,0); \
    acc[2][3] = __builtin_amdgcn_mfma_f32_16x16x32_bf16(af2, bw3, acc[2][3], 0,0,0); \
    acc[3][0] = __builtin_amdgcn_mfma_f32_16x16x32_bf16(af3, bw0, acc[3][0], 0,0,0); \
    acc[3][1] = __builtin_amdgcn_mfma_f32_16x16x32_bf16(af3, bw1, acc[3][1], 0,0,0); \
    acc[3][2] = __builtin_amdgcn_mfma_f32_16x16x32_bf16(af3, bw2, acc[3][2], 0,0,0); \
    acc[3][3] = __builtin_amdgcn_mfma_f32_16x16x32_bf16(af3, bw3, acc[3][3], 0,0,0); \
    if (SKIP && (WITHK)){ \
      accK[0][0] = __builtin_amdgcn_mfma_f32_16x16x32_bf16(af0, bk0, accK[0][0], 0,0,0); \
      accK[0][1] = __builtin_amdgcn_mfma_f32_16x16x32_bf16(af0, bk1, accK[0][1], 0,0,0); \
      accK[0][2] = __builtin_amdgcn_mfma_f32_16x16x32_bf16(af0, bk2, accK[0][2], 0,0,0); \
      accK[0][3] = __builtin_amdgcn_mfma_f32_16x16x32_bf16(af0, bk3, accK[0][3], 0,0,0); \
      accK[1][0] = __builtin_amdgcn_mfma_f32_16x16x32_bf16(af1, bk0, accK[1][0], 0,0,0); \
      accK[1][1] = __builtin_amdgcn_mfma_f32_16x16x32_bf16(af1, bk1, accK[1][1], 0,0,0); \
      accK[1][2] = __builtin_amdgcn_mfma_f32_16x16x32_bf16(af1, bk2, accK[1][2], 0,0,0); \
      accK[1][3] = __builtin_amdgcn_mfma_f32_16x16x32_bf16(af1, bk3, accK[1][3], 0,0,0); \
      accK[2][0] = __builtin_amdgcn_mfma_f32_16x16x32_bf16(af2, bk0, accK[2][0], 0,0,0); \
      accK[2][1] = __builtin_amdgcn_mfma_f32_16x16x32_bf16(af2, bk1, accK[2][1], 0,0,0); \
      accK[2][2] = __builtin_amdgcn_mfma_f32_16x16x32_bf16(af2, bk2, accK[2][2], 0,0,0); \
      accK[2][3] = __builtin_amdgcn_mfma_f32_16x16x32_bf16(af2, bk3, accK[2][3], 0,0,0); \
      accK[3][0] = __builtin_amdgcn_mfma_f32_16x16x32_bf16(af3, bk0, accK[3][0], 0,0,0); \
      accK[3][1] = __builtin_amdgcn_mfma_f32_16x16x32_bf16(af3, bk1, accK[3][1], 0,0,0); \
      accK[3][2] = __builtin_amdgcn_mfma_f32_16x16x32_bf16(af3, bk2, accK[3][2], 0,0,0); \
      accK[3][3] = __builtin_amdgcn_mfma_f32_16x16x32_bf16(af3, bk3, accK[3][3], 0,0,0); \
    } \
    __builtin_amdgcn_s_setprio(0); }

  f32x4 acc[4][4], accK[SKIP?4:1][SKIP?4:1];
  #pragma unroll
  for (int m=0;m<4;m++)
    #pragma unroll
    for (int n=0;n<4;n++){
      acc[m][n] = (f32x4){0.f,0.f,0.f,0.f};
      if (SKIP) accK[m][n] = (f32x4){0.f,0.f,0.f,0.f};
    }
  float bs[4]={0,0,0,0}, bq[4]={0,0,0,0}, bsk[4]={0,0,0,0}, bqk[4]={0,0,0,0};
  float bv[4], bkv[4];
  #pragma unroll
  for (int n=0;n<4;n++){
    bv[n] = bias[64*wc + 16*n + lr];
    bkv[n] = SKIP ? biasK[64*wc + 16*n + lr] : 0.f;
  }

  // barrier: Af/Bf + W staging visible before first WRITEA/use
  PBAR();

  // A prologue: prime 4 sets (k-steps 0..3 of first tile), stage step 0 into buf0
  {
    const int t0 = bid;
    LOADA(0, t0, 0);
    LOADA(1, t0, 1);
    LOADA(2, t0, 2);
    LOADA(3, t0, 3);
    WRITEA(0, 0, 0);
    PBAR();
  }

  for (int tile = bid; tile < NT; tile += gridN){
    const int tnext = tile + gridN;
    const bool hasnext = (tnext < NT);
    STEPBODY(0, 0, 1, LOADA(0, tile, 4));
    WRITEA(1, 1, 1); PBAR();
    STEPBODY(1, 1, 1, LOADA(1, tile, 5));
    WRITEA(2, 0, 2); PBAR();
    STEPBODY(0, 2, 1, LOADA(2, tile, 6));
    WRITEA(3, 1, 3); PBAR();
    STEPBODY(1, 3, 1, LOADA(3, tile, 7));
    WRITEA(0, 0, 4); PBAR();
    STEPBODY(0, 4, 0, if (hasnext) LOADA(0, tnext, 0));
    WRITEA(1, 1, 5); PBAR();
    STEPBODY(1, 5, 0, if (hasnext) LOADA(1, tnext, 1));
    WRITEA(2, 0, 6); PBAR();
    STEPBODY(0, 6, 0, if (hasnext) LOADA(2, tnext, 2));
    WRITEA(3, 1, 7); PBAR();
    STEPBODY(1, 7, 0, if (hasnext) LOADA(3, tnext, 3));
    if (hasnext){ WRITEA(0, 0, 0); PBAR(); }

    // per-tile epilogue (stores overlap next tile's in-flight loads / ds_reads)
    #pragma unroll
    for (int m=0;m<4;m++){
      #pragma unroll
      for (int r=0;r<4;r++){
        int row = tile*128 + 64*wr + 16*m + kq*4 + r;
        if (row < N){
          #pragma unroll
          for (int n=0;n<4;n++){
            int col = 64*wc + 16*n + lr;
            float v = acc[m][n][r] + bv[n];
            C[(size_t)row*D + col] = f2b(v);
            bs[n] += v; bq[n] += v*v;
            if (SKIP){
              float u = accK[m][n][r] + bkv[n];
              Ck[(size_t)row*D + col] = f2b(u);
              bsk[n] += u; bqk[n] += u*u;
            }
          }
        }
      }
    }
    #pragma unroll
    for (int m=0;m<4;m++)
      #pragma unroll
      for (int n=0;n<4;n++){
        acc[m][n] = (f32x4){0.f,0.f,0.f,0.f};
        if (SKIP) accK[m][n] = (f32x4){0.f,0.f,0.f,0.f};
      }
  }
#undef LOADA
#undef WRITEA
#undef PBAR
#undef STEPBODY

  // one stat-reduction per block
  #pragma unroll
  for (int n=0;n<4;n++){
    float s = bs[n], q = bq[n];
    s += __shfl_xor(s,16); s += __shfl_xor(s,32);
    q += __shfl_xor(q,16); q += __shfl_xor(q,32);
    if (kq == 0){
      int col = 64*wc + 16*n + lr;
      atomicAdd(&shS[col], s);
      atomicAdd(&shQ[col], q);
    }
    if (SKIP){
      float sk = bsk[n], qk = bqk[n];
      sk += __shfl_xor(sk,16); sk += __shfl_xor(sk,32);
      qk += __shfl_xor(qk,16); qk += __shfl_xor(qk,32);
      if (kq == 0){
        int col = 64*wc + 16*n + lr;
        atomicAdd(&shSK[col], sk);
        atomicAdd(&shQK[col], qk);
      }
    }
  }
  __syncthreads();
  if (tid < 128){
    unsafeAtomicAdd(&gS[tid], shS[tid]);
    unsafeAtomicAdd(&gQ[tid], shQ[tid]);
    if (SKIP){
      unsafeAtomicAdd(&gSK[tid], shSK[tid]);
      unsafeAtomicAdd(&gQK[tid], shQK[tid]);
    }
  }
}

// ---------------- final: out = relu(bn2(h2) + bn3(skip)), f32 out (BN in-block) -------
__global__ __launch_bounds__(256) void k_final(const ushort* __restrict__ h2,
      const ushort* __restrict__ sk, float* __restrict__ out,
      const float* __restrict__ sum2, const float* __restrict__ sq2,
      const float* __restrict__ g2, const float* __restrict__ be2,
      const float* __restrict__ sum3, const float* __restrict__ sq3,
      const float* __restrict__ g3, const float* __restrict__ be3,
      float invN, long long n4){
  __shared__ float A2[128], B2[128], A3[128], B3[128];
  if (threadIdx.x < 128){
    int c = threadIdx.x;
    float m2 = sum2[c]*invN;
    float v2 = sq2[c]*invN - m2*m2;
    float a2 = g2[c]*rsqrtf(fmaxf(v2, 0.f) + 1e-5f);
    A2[c] = a2; B2[c] = be2[c] - m2*a2;
    float m3 = sum3[c]*invN;
    float v3 = sq3[c]*invN - m3*m3;
    float a3 = g3[c]*rsqrtf(fmaxf(v3, 0.f) + 1e-5f);
    A3[c] = a3; B3[c] = be3[c] - m3*a3;
  }
  __syncthreads();
  long long i = (long long)blockIdx.x*256 + threadIdx.x;
  const long long stride = (long long)gridDim.x*256;
  for (; i < n4; i += stride){
    int c = ((int)(i & 31)) << 2;
    float4 a2 = *reinterpret_cast<const float4*>(A2 + c);
    float4 b2 = *reinterpret_cast<const float4*>(B2 + c);
    float4 a3 = *reinterpret_cast<const float4*>(A3 + c);
    float4 b3 = *reinterpret_cast<const float4*>(B3 + c);
    ushort4 h = reinterpret_cast<const ushort4*>(h2)[i];
    ushort4 s = reinterpret_cast<const ushort4*>(sk)[i];
    float4 v;
    v.x = fmaxf(a2.x*b2f(h.x) + b2.x + a3.x*b2f(s.x) + b3.x, 0.f);
    v.y = fmaxf(a2.y*b2f(h.y) + b2.y + a3.y*b2f(s.y) + b3.y, 0.f);
    v.z = fmaxf(a2.z*b2f(h.z) + b2.z + a3.z*b2f(s.z) + b3.z, 0.f);
    v.w = fmaxf(a2.w*b2f(h.w) + b2.w + a3.w*b2f(s.w) + b3.w, 0.f);
    reinterpret_cast<float4*>(out)[i] = v;
  }
}

extern "C" void kernel_launch(void* const* d_in, const int* in_sizes, int n_in,
                              void* d_out, int out_size, void* d_ws, size_t ws_size,
                              hipStream_t stream) {
  const float* x        = (const float*)d_in[0];
  const int*   src      = (const int*)  d_in[1];
  const int*   dst      = (const int*)  d_in[2];
  const float* w_self1  = (const float*)d_in[3];
  const float* w_neigh1 = (const float*)d_in[4];
  const float* b1       = (const float*)d_in[5];
  const float* w_self2  = (const float*)d_in[6];
  const float* w_neigh2 = (const float*)d_in[7];
  const float* b2       = (const float*)d_in[8];
  const float* w_skip   = (const float*)d_in[9];
  const float* b_skip   = (const float*)d_in[10];
  const float* g1       = (const float*)d_in[11];
  const float* be1      = (const float*)d_in[12];
  const float* g2       = (const float*)d_in[13];
  const float* be2      = (const float*)d_in[14];
  const float* g3       = (const float*)d_in[15];
  const float* be3      = (const float*)d_in[16];
  (void)n_in; (void)ws_size;

  const int N = in_sizes[0] / D;
  const int E = in_sizes[1];
  const int NB = (N + 255) >> 8;
  float* out = (float*)d_out;

  // ---- workspace layout ----
  char* p = (char*)d_ws;
  const size_t nd2 = (((size_t)N * D * 2) + 255) / 256 * 256;   // bf16 [N][D]
  ushort* meanb  = (ushort*)p; p += nd2;
  ushort* h2pre  = (ushort*)p; p += nd2;     // layer-2 pre-BN output
  ushort* hpre_b = (ushort*)p; p += nd2;     // layer-1 pre-BN output (h1pre)
  ushort* skip_b = (ushort*)p; p += nd2;
  ushort* Wb1    = (ushort*)p; p += 256*128*2;
  ushort* Wb2    = (ushort*)p; p += 256*128*2;
  ushort* Wb3    = (ushort*)p; p += 128*128*2;
  int*    offs   = (int*)p;   p += (((size_t)(N+1)*4) + 255) / 256 * 256;
  int*    bcnt   = (int*)p;   p += 2304;
  float*  st     = (float*)p; p += 1536*sizeof(float);
  int*    bbase  = (int*)p;   p += 2304;
  int*    bcur   = (int*)p;   p += 2048;
  float *sum1=st,      *sq1=st+128,  *sum2=st+256, *sq2=st+384, *sum3=st+512, *sq3=st+640;

  // scratch in d_out (dead before k_final rewrites all of d_out)
  const size_t slpad = (((size_t)E*4) + 255) / 256 * 256;
  const size_t xbpad = (((size_t)N*D*2) + 255) / 256 * 256;
  int*      slots = (int*)d_out;
  ushort*   xb    = (ushort*)((char*)d_out + slpad);
  unsigned* pairs = (unsigned*)((char*)d_out + slpad + xbpad);

  hipMemsetAsync(bcnt, 0, 2304 + 1536*sizeof(float), stream);

  const long long n4 = (long long)N * D / 4;

  // --- prep: weight transposes + dst histogram + x cast, one launch ---
  k_prep<<<3392, 256, 0, stream>>>(w_self1, w_neigh1, w_self2, w_neigh2, w_skip,
                                   Wb1, Wb2, Wb3, dst, bcnt, E, x, xb, n4);

  // --- CSR build ---
  k_bscan<<<1, 1024, 0, stream>>>(bcnt, bbase, bcur, NB, E);
  k_part<<<(E + PCHUNK - 1)/PCHUNK, 256, 0, stream>>>(src, dst, bcur, pairs, E);
  k_sortb<<<NB, 256, 0, stream>>>(pairs, bbase, offs, slots, N, NB);

  const int gablocks = (N + 3) / 4;
  const int NT = (N + 127) / 128;
  const int gpersist = 256;                 // 1 persistent block per CU (142KB LDS)
  const float invN = 1.0f / (float)N;

  // --- layer 1 ---
  k_gatherb<false><<<gablocks, 256, 0, stream>>>(xb, slots, offs, meanb, N,
                                                 nullptr, nullptr, nullptr, nullptr, 0.f);
  k_mfma<false><<<gpersist, 256, 0, stream>>>(xb, meanb, Wb1, nullptr, b1, nullptr,
                                              hpre_b, nullptr, sum1, sq1, nullptr, nullptr,
                                              N, NT, nullptr, nullptr, nullptr, nullptr, 0.f);

  // --- layer 2: gather applies BN+ReLU inline (reads h1pre; no separate BN pass) ---
  k_gatherb<true><<<gablocks, 256, 0, stream>>>(hpre_b, slots, offs, meanb, N,
                                                sum1, sq1, g1, be1, invN);

  // fused layer-2 + skip GEMM; self-half BN applied during A-staging
  k_mfma<true><<<gpersist, 256, 0, stream>>>(hpre_b, meanb, Wb2, Wb3, b2, b_skip,
                                             h2pre, skip_b, sum2, sq2, sum3, sq3,
                                             N, NT, sum1, sq1, g1, be1, invN);

  k_final<<<4096, 256, 0, stream>>>(h2pre, skip_b, out,
                                    sum2, sq2, g2, be2, sum3, sq3, g3, be3, invN, n4);
}